// Round 8
// baseline (332.047 us; speedup 1.0000x reference)
//
#include <hip/hip_runtime.h>
#include <hip/hip_bf16.h>

using bf16 = __hip_bfloat16;

#define DI __device__ __forceinline__

typedef __attribute__((ext_vector_type(8))) short short8;
typedef __attribute__((ext_vector_type(8))) unsigned short u16x8;
typedef __attribute__((ext_vector_type(4))) unsigned short u16x4;
typedef __attribute__((ext_vector_type(4))) float f32x4;

#define MFMA_BF16 __builtin_amdgcn_mfma_f32_16x16x32_bf16

DI float leaky(float x) { return x > 0.f ? x : 0.1f * x; }

// bf16 split helpers (RNE). x = hi + lo to ~2^-16 relative.
DI unsigned short b16(float x) {
  union { float f; unsigned u; } v; v.f = x;
  unsigned r = v.u + 0x7FFFu + ((v.u >> 16) & 1u);
  return (unsigned short)(r >> 16);
}
DI float fromb16(unsigned short h) {
  union { unsigned u; float f; } v; v.u = ((unsigned)h) << 16; return v.f;
}

// Problem constants: B=2, C=64, H=64, W=64, N=4096. Inputs fp32 (R3/R4).
// NOTE R13: hipLaunchCooperativeKernel fails silently under graph capture here.
// Precision ladder (validated): Q/K split bf16, P hi-only, V hi-only in PV,
// L via ones-row MFMA. R2: swapped QK^T -> lane owns one pixel.
// R4: convs channel-split. ATTN LESSONS (R5-R7): 8-wave K-split loses (barrier
// domain), launch_bounds reg-pinning spills, V-direct-from-global loses (~6us,
// vmcnt couples V loads to K prefetch). R4's attn (71.7us) is the local
// optimum -> reverted exactly; attn frozen.
// R8: convs+proj were LDS-read-bound (9 b128 weight broadcasts vs 36 FMA per
// channel). All conv weights are block-uniform -> read straight from global
// (compiler emits s_load to SGPR, scalar pipe, dual-issue). Proj activations
// are wave-uniform (grp const per wave) -> readfirstlane + uniform global
// reads; weights per-lane from LDS stride-65 (conflict-free).
static constexpr int N_ = 4096;
static constexpr size_t CN = 262144;
static constexpr size_t BCN = 524288;

// ---- Workspace layout (float indices) ----
static constexpr size_t XG_OFF = 137104;
static constexpr size_t GG_OFF = XG_OFF + BCN;
static constexpr size_t QX_OFF = GG_OFF + BCN;
static constexpr size_t KX_OFF = QX_OFF + BCN;
static constexpr size_t VX_OFF = KX_OFF + BCN;
static constexpr size_t QG_OFF = VX_OFF + BCN;
static constexpr size_t KG_OFF = QG_OFF + BCN;
static constexpr size_t P1X_OFF = KG_OFF + BCN;
static constexpr size_t P1G_OFF = P1X_OFF + BCN;
static constexpr size_t ML_OFF  = P1G_OFF + BCN;
static constexpr size_t MLL_OFF = ML_OFF + 32768;
static constexpr size_t CA_OFF = ML_OFF;   // 256 floats; consumed by coordconv before attn writes ML
static constexpr size_t OB_OFF = QX_OFF;
static constexpr size_t UB_OFF = KX_OFF;
static constexpr size_t GO_OFF = GG_OFF;
static constexpr size_t QXH_U = QX_OFF * 2, QXL_U = QXH_U + BCN;
static constexpr size_t KXH_U = KX_OFF * 2, KXL_U = KXH_U + BCN;
static constexpr size_t VXH_U = VX_OFF * 2;
static constexpr size_t QGH_U = QG_OFF * 2, QGL_U = QGH_U + BCN;
static constexpr size_t KGH_U = KG_OFF * 2, KGL_U = KGH_U + BCN;
// Peak 19.7 MB (validated R6-R14)

// ---------------- K0: channel-attention scales (256 = src*128 + b*64 + ch) ----------------
__global__ __launch_bounds__(64) void k_ca(const float* __restrict__ x,
                                           const float* __restrict__ g,
                                           const float* __restrict__ lw_p,
                                           const float* __restrict__ lb_p,
                                           float* __restrict__ ws) {
  int blk = blockIdx.x;
  int ch = blk & 63; blk >>= 6;
  int b  = blk & 1;  blk >>= 1;
  int src = blk;
  const float* in = (src ? g : x) + ((size_t)(b * 64 + ch)) * N_;
  int t = threadIdx.x;
  float s = 0.f;
#pragma unroll
  for (int i = 0; i < 16; ++i) {
    float4 v = *reinterpret_cast<const float4*>(in + i * 256 + t * 4);
    s += (v.x + v.y) + (v.z + v.w);
  }
#pragma unroll
  for (int d = 1; d < 64; d <<= 1) s += __shfl_xor(s, d, 64);
  if (t == 0) {
    float p = s * (1.f / 4096.f);
    float lwv = lw_p[0], lbv = lb_p[0];
    float h = leaky(lwv * p + lbv);
    ws[CA_OFF + (src * 2 + b) * 64 + ch] = 1.f / (1.f + expf(-(lwv * h + lbv)));
  }
}

// ---------------- K1: coord-conv 3x3, channel-split, scalar-pipe weights ----------------
__global__ __launch_bounds__(256) void k_coordconv(const float* __restrict__ x,
                                                   const float* __restrict__ g,
                                                   const float* __restrict__ cw,
                                                   float* __restrict__ ws) {
  int blk = blockIdx.x;  // 4096 = src*2048 + b*1024 + og*64 + row
  int row = blk & 63; blk >>= 6;
  int og  = blk & 15; blk >>= 4;
  int b   = blk & 1;  blk >>= 1;
  int src = blk;
  int o0 = og * 4;
  const float* in = src ? g : x;
  float* outp = ws + (src ? GG_OFF : XG_OFF);
  const float* cwB = cw + (size_t)o0 * 594;   // block-uniform -> s_load weights
  __shared__ float part[4][4][64];
  int t = threadIdx.x;
  int wv = t >> 6, px = t & 63;
  int rm = row - 1, rp = row + 1;
  int rmc = rm < 0 ? 0 : rm, rpc = rp > 63 ? 63 : rp;
  float maskm = rm < 0 ? 0.f : 1.f, maskp = rp > 63 ? 0.f : 1.f;
  int c0 = wv * 16;
  const float* base = in + ((size_t)(b * 64 + c0)) * N_ + px;
  float ra[16], rb[16], rc[16];
#pragma unroll
  for (int i = 0; i < 16; ++i) {
    ra[i] = base[(size_t)i * N_ + (size_t)rmc * 64] * maskm;
    rb[i] = base[(size_t)i * N_ + (size_t)row * 64];
    rc[i] = base[(size_t)i * N_ + (size_t)rpc * 64] * maskp;
  }
  float acc[4] = {};
  auto tap9 = [&](int ch, float va, float vb, float vc) {
    float la = __shfl_up(va, 1, 64);   if (px == 0)  la = 0.f;
    float ga = __shfl_down(va, 1, 64); if (px == 63) ga = 0.f;
    float lb = __shfl_up(vb, 1, 64);   if (px == 0)  lb = 0.f;
    float gb = __shfl_down(vb, 1, 64); if (px == 63) gb = 0.f;
    float lc = __shfl_up(vc, 1, 64);   if (px == 0)  lc = 0.f;
    float gc = __shfl_down(vc, 1, 64); if (px == 63) gc = 0.f;
#pragma unroll
    for (int oo = 0; oo < 4; ++oo) {
      const float* wq = cwB + (size_t)oo * 594 + ch * 9;   // uniform -> SGPR
      float s = acc[oo];
      s = fmaf(wq[0], la, s); s = fmaf(wq[1], va, s); s = fmaf(wq[2], ga, s);
      s = fmaf(wq[3], lb, s); s = fmaf(wq[4], vb, s); s = fmaf(wq[5], gb, s);
      s = fmaf(wq[6], lc, s); s = fmaf(wq[7], vc, s); s = fmaf(wq[8], gc, s);
      acc[oo] = s;
    }
  };
#pragma unroll
  for (int i = 0; i < 16; ++i) tap9(c0 + i, ra[i], rb[i], rc[i]);
  if (wv == 3) {
    // ch 64: xx varies along px (zero-padded rows/cols like real channels)
    float xx = (float)px * (2.f / 63.f) - 1.f;
    tap9(64, maskm * xx, xx, maskp * xx);
    // ch 65: yy constant along px, varies by row
    float ya = maskm * ((float)rm * (2.f / 63.f) - 1.f);
    float yb = (float)row * (2.f / 63.f) - 1.f;
    float yc = maskp * ((float)rp * (2.f / 63.f) - 1.f);
    tap9(65, ya, yb, yc);
  }
#pragma unroll
  for (int oo = 0; oo < 4; ++oo) part[wv][oo][px] = acc[oo];
  __syncthreads();
  int oc = t >> 6;
  float s = (part[0][oc][px] + part[1][oc][px]) + (part[2][oc][px] + part[3][oc][px]);
  float cav = ws[CA_OFF + (src * 2 + b) * 64 + o0 + oc];
  outp[((size_t)(b * 64 + o0 + oc)) * N_ + (size_t)row * 64 + px] = s * cav;
}

// ---------------- K2: 1x1 projections; uniform activations via s_load, weights per-lane LDS ----------------
__global__ __launch_bounds__(256) void k_proj(float* __restrict__ ws,
                                              const float* __restrict__ xqw, const float* __restrict__ xqb,
                                              const float* __restrict__ xkw, const float* __restrict__ xkb,
                                              const float* __restrict__ xvw, const float* __restrict__ xvb,
                                              const float* __restrict__ gqw, const float* __restrict__ gqb,
                                              const float* __restrict__ gkw, const float* __restrict__ gkb) {
  int blk = blockIdx.x;  // 5 * 2 * 64
  int pt = blk & 63; blk >>= 6;
  int b  = blk & 1;  blk >>= 1;
  int which = blk;
  size_t in_o;
  const float *wp, *bp;
  size_t hU = 0, lU = 0;
  if (which == 0)      { in_o = XG_OFF; wp = xqw; bp = xqb; hU = QXH_U; lU = QXL_U; }
  else if (which == 1) { in_o = XG_OFF; wp = xkw; bp = xkb; hU = KXH_U; lU = KXL_U; }
  else if (which == 2) { in_o = XG_OFF; wp = xvw; bp = xvb; }
  else if (which == 3) { in_o = GG_OFF; wp = gqw; bp = gqb; hU = QGH_U; lU = QGL_U; }
  else                 { in_o = GG_OFF; wp = gkw; bp = gkb; hU = KGH_U; lU = KGL_U; }

  __shared__ float wl[64 * 65];
  __shared__ float bl[64];
  unsigned short* us = (unsigned short*)ws;
  int t = threadIdx.x;
  int pb = pt * 64;
  for (int idx = t; idx < 4096; idx += 256)
    wl[(idx >> 6) * 65 + (idx & 63)] = wp[idx];
  if (t < 64) bl[t] = bp[t];
  __syncthreads();
  int o = t & 63, grp = t >> 6;
  int grpu = __builtin_amdgcn_readfirstlane(grp);   // wave-uniform -> scalar loads
  const float* xu = ws + in_o + (size_t)b * CN + pb + grpu * 16;
  const float* wr = &wl[o * 65];
  float acc[16];
  float bv = bl[o];
#pragma unroll
  for (int j = 0; j < 16; ++j) acc[j] = bv;
  for (int c = 0; c < 64; ++c) {
    float wv = wr[c];
    const float4* xb = reinterpret_cast<const float4*>(xu + (size_t)c * N_);
    float4 t0 = xb[0], t1 = xb[1], t2 = xb[2], t3 = xb[3];
    acc[0] = fmaf(wv, t0.x, acc[0]);   acc[1] = fmaf(wv, t0.y, acc[1]);
    acc[2] = fmaf(wv, t0.z, acc[2]);   acc[3] = fmaf(wv, t0.w, acc[3]);
    acc[4] = fmaf(wv, t1.x, acc[4]);   acc[5] = fmaf(wv, t1.y, acc[5]);
    acc[6] = fmaf(wv, t1.z, acc[6]);   acc[7] = fmaf(wv, t1.w, acc[7]);
    acc[8] = fmaf(wv, t2.x, acc[8]);   acc[9] = fmaf(wv, t2.y, acc[9]);
    acc[10] = fmaf(wv, t2.z, acc[10]); acc[11] = fmaf(wv, t2.w, acc[11]);
    acc[12] = fmaf(wv, t3.x, acc[12]); acc[13] = fmaf(wv, t3.y, acc[13]);
    acc[14] = fmaf(wv, t3.z, acc[14]); acc[15] = fmaf(wv, t3.w, acc[15]);
  }
  if (which != 2) {
#pragma unroll
    for (int j = 0; j < 16; ++j) {
      size_t idx = ((size_t)b * N_ + pb + grp * 16 + j) * 64 + o;
      unsigned short hi = b16(acc[j]);
      us[hU + idx] = hi;
      us[lU + idx] = b16(acc[j] - fromb16(hi));
    }
  } else {
    __syncthreads();
    float* ot = wl;
#pragma unroll
    for (int j = 0; j < 16; ++j) ot[o * 65 + grp * 16 + j] = acc[j];
    __syncthreads();
    int o2 = t >> 2;
#pragma unroll
    for (int e = 0; e < 4; ++e) {
      int px = (t & 3) * 16 + e * 4;
      u16x4 hv;
#pragma unroll
      for (int q = 0; q < 4; ++q) hv[q] = b16(ot[o2 * 65 + px + q]);
      size_t idx = ((size_t)(b * 64 + o2)) * N_ + pb + px;
      *reinterpret_cast<u16x4*>(&us[VXH_U + idx]) = hv;
    }
  }
}

// ---------------- K3: MFMA flash attention (R4 exact: Vth LDS dbuf, scalar P, per-lane softmax) ----------------
__global__ __launch_bounds__(256) void k_attn(float* __restrict__ ws) {
  unsigned short* us = (unsigned short*)ws;
  int blk = blockIdx.x;
  int half = blk & 1; blk >>= 1;
  int qt = blk & 63;  blk >>= 6;
  int b  = blk & 1;   blk >>= 1;
  int at = blk;
  const unsigned short* QH = us + (at ? QGH_U : QXH_U);
  const unsigned short* QL = us + (at ? QGL_U : QXL_U);
  const unsigned short* KHg = us + (at ? KGH_U : KXH_U);
  const unsigned short* KLg = us + (at ? KGL_U : KXL_U);
  const unsigned short* VHg = us + VXH_U;
  float* Pg = ws + (at ? (half ? P1G_OFF : GG_OFF) : (half ? P1X_OFF : XG_OFF))
            + (size_t)b * CN + qt * 64;

  __shared__ unsigned short Kh[2][4096], Kl[2][4096], Vth[2][4096], Ph[4096];

  int t = threadIdx.x;
  int w = t >> 6, lane = t & 63, quad = lane >> 4, l15 = lane & 15;
  int swz = l15 & 7;

  short8 qh[2], ql[2];
  {
    size_t qbase = ((size_t)b * N_ + qt * 64 + 16 * w + l15) * 64;
#pragma unroll
    for (int ks = 0; ks < 2; ++ks) {
      qh[ks] = *reinterpret_cast<const short8*>(&QH[qbase + ks * 32 + quad * 8]);
      ql[ks] = *reinterpret_cast<const short8*>(&QL[qbase + ks * 32 + quad * 8]);
    }
  }

  short8 ones;
#pragma unroll
  for (int j = 0; j < 8; ++j) ones[j] = (short)0x3F80;  // bf16 1.0

  int mt0 = half * 32, mt1 = half * 32 + 32;

  u16x8 rkh[2], rkl[2], rvh[2];
  size_t ko = ((size_t)b * N_ + (size_t)mt0 * 64 + (t >> 3)) * 64 + (size_t)(t & 7) * 8;
  size_t vo = ((size_t)(b * 64) + (t >> 3)) * N_ + (size_t)mt0 * 64 + (size_t)(t & 7) * 8;
  auto prefetch = [&]() {
    rkh[0] = *reinterpret_cast<const u16x8*>(&KHg[ko]);
    rkl[0] = *reinterpret_cast<const u16x8*>(&KLg[ko]);
    rkh[1] = *reinterpret_cast<const u16x8*>(&KHg[ko + 2048]);
    rkl[1] = *reinterpret_cast<const u16x8*>(&KLg[ko + 2048]);
    rvh[0] = *reinterpret_cast<const u16x8*>(&VHg[vo]);
    rvh[1] = *reinterpret_cast<const u16x8*>(&VHg[vo + (size_t)32 * N_]);
    ko += 4096; vo += 64;
  };
  int wr0 = t >> 3, wch = t & 7;
  int woff = wr0 * 64 + ((wch ^ (wr0 & 7)) << 3);
  auto writebuf = [&](int par) {
    *reinterpret_cast<u16x8*>(&Kh[par][woff]) = rkh[0];
    *reinterpret_cast<u16x8*>(&Kl[par][woff]) = rkl[0];
    *reinterpret_cast<u16x8*>(&Vth[par][woff]) = rvh[0];
    *reinterpret_cast<u16x8*>(&Kh[par][woff + 2048]) = rkh[1];
    *reinterpret_cast<u16x8*>(&Kl[par][woff + 2048]) = rkl[1];
    *reinterpret_cast<u16x8*>(&Vth[par][woff + 2048]) = rvh[1];
  };

  f32x4 Oa[4] = {{0.f, 0.f, 0.f, 0.f}, {0.f, 0.f, 0.f, 0.f},
                 {0.f, 0.f, 0.f, 0.f}, {0.f, 0.f, 0.f, 0.f}};
  f32x4 La = {0.f, 0.f, 0.f, 0.f};   // L in element 0 (ones-row MFMA; rows identical)
  float M = -1e30f;                  // per-lane: pixel n = 16w + l15

  int phb = (16 * w + l15) * 64;
  int mh = quad >> 1, mlw = (quad & 1) * 4;

  prefetch();
  writebuf(0);
  __syncthreads();
  for (int mt = mt0; mt < mt1; ++mt) {
    int pb = (mt - mt0) & 1;
    if (mt + 1 < mt1) prefetch();  // global latency overlaps tile compute

    // S^T[m][n]: m = ms*16 + quad*4 + reg, n = 16w + l15 (swapped operands)
    f32x4 S[4];
    __builtin_amdgcn_s_setprio(1);
#pragma unroll
    for (int ms = 0; ms < 4; ++ms) {
      f32x4 a0 = {0.f, 0.f, 0.f, 0.f}, a1 = {0.f, 0.f, 0.f, 0.f};
      int row = ms * 16 + l15;
#pragma unroll
      for (int ks = 0; ks < 2; ++ks) {
        int off = row * 64 + (((ks * 4 + quad) ^ swz) << 3);
        short8 khf = *reinterpret_cast<const short8*>(&Kh[pb][off]);
        short8 klf = *reinterpret_cast<const short8*>(&Kl[pb][off]);
        f32x4& a = ks ? a1 : a0;
        a = MFMA_BF16(khf, ql[ks], a, 0, 0, 0);
        a = MFMA_BF16(klf, qh[ks], a, 0, 0, 0);
        a = MFMA_BF16(khf, qh[ks], a, 0, 0, 0);
      }
      S[ms] = a0 + a1;
    }
    __builtin_amdgcn_s_setprio(0);

    // in-lane max over 16 values + 2-step cross-quad butterfly
    float m0 = fmaxf(fmaxf(S[0][0], S[0][1]), fmaxf(S[0][2], S[0][3]));
    float m1 = fmaxf(fmaxf(S[1][0], S[1][1]), fmaxf(S[1][2], S[1][3]));
    float m2 = fmaxf(fmaxf(S[2][0], S[2][1]), fmaxf(S[2][2], S[2][3]));
    float m3 = fmaxf(fmaxf(S[3][0], S[3][1]), fmaxf(S[3][2], S[3][3]));
    float tm = fmaxf(fmaxf(m0, m1), fmaxf(m2, m3));
    tm = fmaxf(tm, __shfl_xor(tm, 16, 64));
    tm = fmaxf(tm, __shfl_xor(tm, 32, 64));
    float mn = fmaxf(M, tm);
    float al = __expf(M - mn);
    M = mn;
#pragma unroll
    for (int ms = 0; ms < 4; ++ms) {
      int goff = phb + ((((ms << 1) + mh) ^ swz) << 3) + mlw;
#pragma unroll
      for (int r = 0; r < 4; ++r) {
        float p = __expf(S[ms][r] - mn);
        Ph[goff + r] = b16(p);   // wave-private rows -> no barrier needed
      }
    }
#pragma unroll
    for (int cs = 0; cs < 4; ++cs) {
      Oa[cs][0] *= al; Oa[cs][1] *= al; Oa[cs][2] *= al; Oa[cs][3] *= al;
    }
    La[0] *= al;

    // O^T += V^T P^T, V hi-only: 10 MFMAs (incl. 2 ones-row for L), 10 ds_reads/tile
    __builtin_amdgcn_s_setprio(1);
#pragma unroll
    for (int ks = 0; ks < 2; ++ks) {
      int poff = phb + (((ks * 4 + quad) ^ swz) << 3);
      short8 phf = *reinterpret_cast<const short8*>(&Ph[poff]);
      La = MFMA_BF16(ones, phf, La, 0, 0, 0);   // row-sums of P == L partials
#pragma unroll
      for (int cs = 0; cs < 4; ++cs) {
        int voff = (cs * 16 + l15) * 64 + (((ks * 4 + quad) ^ swz) << 3);
        short8 vhf = *reinterpret_cast<const short8*>(&Vth[pb][voff]);
        Oa[cs] = MFMA_BF16(vhf, phf, Oa[cs], 0, 0, 0);
      }
    }
    __builtin_amdgcn_s_setprio(0);

    if (mt + 1 < mt1) writebuf(pb ^ 1);  // fenced by previous iteration's barrier
    __syncthreads();
  }

#pragma unroll
  for (int cs = 0; cs < 4; ++cs) {
#pragma unroll
    for (int r = 0; r < 4; ++r) {
      int c = cs * 16 + quad * 4 + r;
      Pg[(size_t)c * N_ + 16 * w + l15] = Oa[cs][r];
    }
  }
  if (quad == 0) {
    int mlb = ((at * 2 + half) * 2 + b) * 4096 + qt * 64 + 16 * w + l15;
    ws[ML_OFF + mlb] = M;
    ws[MLL_OFF + mlb] = La[0];   // La col = pixel 16w+l15, rows identical
  }
}

// ---------------- K4: merge halves + combine ----------------
__global__ __launch_bounds__(256) void k_merge(float* __restrict__ ws,
                                               const float* __restrict__ gm_p,
                                               const float* __restrict__ al_p) {
  size_t i4 = (size_t)blockIdx.x * 256 + threadIdx.x;
  size_t i = i4 * 4;
  int n = (int)(i & 4095);
  int b = (int)(i >> 18);
  float gm = gm_p[0], al = al_p[0];
  float4 p0x = *reinterpret_cast<const float4*>(ws + XG_OFF + i);
  float4 p1x = *reinterpret_cast<const float4*>(ws + P1X_OFF + i);
  float4 p0g = *reinterpret_cast<const float4*>(ws + GG_OFF + i);
  float4 p1g = *reinterpret_cast<const float4*>(ws + P1G_OFF + i);
  float4 M0x = *reinterpret_cast<const float4*>(ws + ML_OFF  + (0 + b) * 4096 + n);
  float4 L0x = *reinterpret_cast<const float4*>(ws + MLL_OFF + (0 + b) * 4096 + n);
  float4 M1x = *reinterpret_cast<const float4*>(ws + ML_OFF  + (2 + b) * 4096 + n);
  float4 L1x = *reinterpret_cast<const float4*>(ws + MLL_OFF + (2 + b) * 4096 + n);
  float4 M0g = *reinterpret_cast<const float4*>(ws + ML_OFF  + (4 + b) * 4096 + n);
  float4 L0g = *reinterpret_cast<const float4*>(ws + MLL_OFF + (4 + b) * 4096 + n);
  float4 M1g = *reinterpret_cast<const float4*>(ws + ML_OFF  + (6 + b) * 4096 + n);
  float4 L1g = *reinterpret_cast<const float4*>(ws + MLL_OFF + (6 + b) * 4096 + n);
  const float* p0xv = (const float*)&p0x; const float* p1xv = (const float*)&p1x;
  const float* p0gv = (const float*)&p0g; const float* p1gv = (const float*)&p1g;
  const float* m0xv = (const float*)&M0x; const float* l0xv = (const float*)&L0x;
  const float* m1xv = (const float*)&M1x; const float* l1xv = (const float*)&L1x;
  const float* m0gv = (const float*)&M0g; const float* l0gv = (const float*)&L0g;
  const float* m1gv = (const float*)&M1g; const float* l1gv = (const float*)&L1g;
  float4 go, ob;
  float* gov = (float*)&go; float* obv = (float*)&ob;
#pragma unroll
  for (int l = 0; l < 4; ++l) {
    float mx = fmaxf(m0xv[l], m1xv[l]);
    float w0 = __expf(m0xv[l] - mx), w1 = __expf(m1xv[l] - mx);
    float xc = (p0xv[l] * w0 + p1xv[l] * w1) / (l0xv[l] * w0 + l1xv[l] * w1);
    float mg = fmaxf(m0gv[l], m1gv[l]);
    float v0 = __expf(m0gv[l] - mg), v1 = __expf(m1gv[l] - mg);
    float gc = (p0gv[l] * v0 + p1gv[l] * v1) / (l0gv[l] * v0 + l1gv[l] * v1);
    gov[l] = gc;
    obv[l] = gm * xc + al * gc;
  }
  *reinterpret_cast<float4*>(ws + GG_OFF + i) = go;  // GO
  *reinterpret_cast<float4*>(ws + QX_OFF + i) = ob;  // OB
}

// ---------------- K5: u = leaky(conv3x3(leaky(out), c1)), channel-split, scalar weights ----------------
__global__ __launch_bounds__(256) void k_conv1(float* __restrict__ ws,
                                               const float* __restrict__ c1w,
                                               const float* __restrict__ c1b) {
  int blk = blockIdx.x;  // 2048 = b*1024 + og*64 + row
  int row = blk & 63; blk >>= 6;
  int og  = blk & 15; blk >>= 4;
  int b   = blk;
  int o0 = og * 4;
  const float* cwB = c1w + (size_t)o0 * 576;   // block-uniform -> s_load weights
  __shared__ float part[4][4][64];
  int t = threadIdx.x;
  int wv = t >> 6, px = t & 63;
  int rm = row - 1, rp = row + 1;
  int rmc = rm < 0 ? 0 : rm, rpc = rp > 63 ? 63 : rp;
  float maskm = rm < 0 ? 0.f : 1.f, maskp = rp > 63 ? 0.f : 1.f;
  int c0 = wv * 16;
  const float* base = ws + OB_OFF + (size_t)b * CN + (size_t)c0 * N_ + px;
  float ra[16], rb[16], rc[16];
#pragma unroll
  for (int i = 0; i < 16; ++i) {
    ra[i] = leaky(base[(size_t)i * N_ + (size_t)rmc * 64]) * maskm;
    rb[i] = leaky(base[(size_t)i * N_ + (size_t)row * 64]);
    rc[i] = leaky(base[(size_t)i * N_ + (size_t)rpc * 64]) * maskp;
  }
  float acc[4] = {};
  auto tap9 = [&](int ch, float va, float vb, float vc) {
    float la = __shfl_up(va, 1, 64);   if (px == 0)  la = 0.f;
    float ga = __shfl_down(va, 1, 64); if (px == 63) ga = 0.f;
    float lb = __shfl_up(vb, 1, 64);   if (px == 0)  lb = 0.f;
    float gb = __shfl_down(vb, 1, 64); if (px == 63) gb = 0.f;
    float lc = __shfl_up(vc, 1, 64);   if (px == 0)  lc = 0.f;
    float gc = __shfl_down(vc, 1, 64); if (px == 63) gc = 0.f;
#pragma unroll
    for (int oo = 0; oo < 4; ++oo) {
      const float* wq = cwB + (size_t)oo * 576 + ch * 9;   // uniform -> SGPR
      float s = acc[oo];
      s = fmaf(wq[0], la, s); s = fmaf(wq[1], va, s); s = fmaf(wq[2], ga, s);
      s = fmaf(wq[3], lb, s); s = fmaf(wq[4], vb, s); s = fmaf(wq[5], gb, s);
      s = fmaf(wq[6], lc, s); s = fmaf(wq[7], vc, s); s = fmaf(wq[8], gc, s);
      acc[oo] = s;
    }
  };
#pragma unroll
  for (int i = 0; i < 16; ++i) tap9(c0 + i, ra[i], rb[i], rc[i]);
#pragma unroll
  for (int oo = 0; oo < 4; ++oo) part[wv][oo][px] = acc[oo];
  __syncthreads();
  int oc = t >> 6;
  float s = (part[0][oc][px] + part[1][oc][px]) + (part[2][oc][px] + part[3][oc][px]);
  float* ub = ws + UB_OFF + (size_t)b * CN;
  ub[(size_t)(o0 + oc) * N_ + (size_t)row * 64 + px] = leaky(s + c1b[o0 + oc]);
}

// ---------------- K6: final, channel-split + fused sc dot, scalar weights ----------------
__global__ __launch_bounds__(256) void k_final(const float* __restrict__ ws,
                                               const float* __restrict__ c2w,
                                               const float* __restrict__ c2b,
                                               const float* __restrict__ scw,
                                               const float* __restrict__ scb,
                                               float* __restrict__ out) {
  int blk = blockIdx.x;  // 2048 = b*1024 + og*64 + row
  int row = blk & 63; blk >>= 6;
  int og  = blk & 15; blk >>= 4;
  int b   = blk;
  int o0 = og * 4;
  const float* cwB = c2w + (size_t)o0 * 576;
  const float* swB = scw + (size_t)o0 * 64;
  __shared__ float part[4][4][64];
  __shared__ float part2[4][4][64];
  int t = threadIdx.x;
  int wv = t >> 6, px = t & 63;
  int rm = row - 1, rp = row + 1;
  int rmc = rm < 0 ? 0 : rm, rpc = rp > 63 ? 63 : rp;
  float maskm = rm < 0 ? 0.f : 1.f, maskp = rp > 63 ? 0.f : 1.f;
  int c0 = wv * 16;
  const float* base = ws + UB_OFF + (size_t)b * CN + (size_t)c0 * N_ + px;
  const float* obb  = ws + OB_OFF + (size_t)b * CN + (size_t)c0 * N_ + (size_t)row * 64 + px;
  float ra[16], rb[16], rc[16], ob[16];
#pragma unroll
  for (int i = 0; i < 16; ++i) {
    ra[i] = base[(size_t)i * N_ + (size_t)rmc * 64] * maskm;
    rb[i] = base[(size_t)i * N_ + (size_t)row * 64];
    rc[i] = base[(size_t)i * N_ + (size_t)rpc * 64] * maskp;
    ob[i] = obb[(size_t)i * N_];
  }
  float acc[4] = {};
  float scp[4] = {};
  auto tap9 = [&](int ch, float va, float vb, float vc) {
    float la = __shfl_up(va, 1, 64);   if (px == 0)  la = 0.f;
    float ga = __shfl_down(va, 1, 64); if (px == 63) ga = 0.f;
    float lb = __shfl_up(vb, 1, 64);   if (px == 0)  lb = 0.f;
    float gb = __shfl_down(vb, 1, 64); if (px == 63) gb = 0.f;
    float lc = __shfl_up(vc, 1, 64);   if (px == 0)  lc = 0.f;
    float gc = __shfl_down(vc, 1, 64); if (px == 63) gc = 0.f;
#pragma unroll
    for (int oo = 0; oo < 4; ++oo) {
      const float* wq = cwB + (size_t)oo * 576 + ch * 9;   // uniform -> SGPR
      float s = acc[oo];
      s = fmaf(wq[0], la, s); s = fmaf(wq[1], va, s); s = fmaf(wq[2], ga, s);
      s = fmaf(wq[3], lb, s); s = fmaf(wq[4], vb, s); s = fmaf(wq[5], gb, s);
      s = fmaf(wq[6], lc, s); s = fmaf(wq[7], vc, s); s = fmaf(wq[8], gc, s);
      acc[oo] = s;
    }
  };
#pragma unroll
  for (int i = 0; i < 16; ++i) {
    tap9(c0 + i, ra[i], rb[i], rc[i]);
#pragma unroll
    for (int oo = 0; oo < 4; ++oo)
      scp[oo] = fmaf(swB[(size_t)oo * 64 + c0 + i], ob[i], scp[oo]);
  }
#pragma unroll
  for (int oo = 0; oo < 4; ++oo) {
    part[wv][oo][px] = acc[oo];
    part2[wv][oo][px] = scp[oo];
  }
  __syncthreads();
  int oc = t >> 6;
  float s  = (part[0][oc][px] + part[1][oc][px]) + (part[2][oc][px] + part[3][oc][px]);
  float sc = (part2[0][oc][px] + part2[1][oc][px]) + (part2[2][oc][px] + part2[3][oc][px]);
  const float* go = ws + GO_OFF + (size_t)b * CN;
  size_t pix = (size_t)row * 64 + px;
  float gvv = go[(size_t)(o0 + oc) * N_ + pix];
  out[(size_t)b * CN + (size_t)(o0 + oc) * N_ + pix] =
      (s + c2b[o0 + oc]) + (sc + scb[o0 + oc]) * gvv;
}

extern "C" void kernel_launch(void* const* d_in, const int* in_sizes, int n_in,
                              void* d_out, int out_size, void* d_ws, size_t ws_size,
                              hipStream_t stream) {
  const float* x     = (const float*)d_in[0];
  const float* guide = (const float*)d_in[1];
  const float* lin_w = (const float*)d_in[2];
  const float* lin_b = (const float*)d_in[3];
  const float* cw    = (const float*)d_in[4];
  const float* xq_w  = (const float*)d_in[5];
  const float* xq_b  = (const float*)d_in[6];
  const float* xk_w  = (const float*)d_in[7];
  const float* xk_b  = (const float*)d_in[8];
  const float* xv_w  = (const float*)d_in[9];
  const float* xv_b  = (const float*)d_in[10];
  const float* gq_w  = (const float*)d_in[11];
  const float* gq_b  = (const float*)d_in[12];
  const float* gk_w  = (const float*)d_in[13];
  const float* gk_b  = (const float*)d_in[14];
  const float* gamma = (const float*)d_in[15];
  const float* alpha = (const float*)d_in[16];
  const float* c1_w  = (const float*)d_in[17];
  const float* c1_b  = (const float*)d_in[18];
  const float* c2_w  = (const float*)d_in[19];
  const float* c2_b  = (const float*)d_in[20];
  const float* sc_w  = (const float*)d_in[21];
  const float* sc_b  = (const float*)d_in[22];
  float* out = (float*)d_out;
  float* ws = (float*)d_ws;

  k_ca<<<256, 64, 0, stream>>>(x, guide, lin_w, lin_b, ws);
  k_coordconv<<<4096, 256, 0, stream>>>(x, guide, cw, ws);
  k_proj<<<640, 256, 0, stream>>>(ws, xq_w, xq_b, xk_w, xk_b, xv_w, xv_b,
                                  gq_w, gq_b, gk_w, gk_b);
  k_attn<<<512, 256, 0, stream>>>(ws);
  k_merge<<<512, 256, 0, stream>>>(ws, gamma, alpha);
  k_conv1<<<2048, 256, 0, stream>>>(ws, c1_w, c1_b);
  k_final<<<2048, 256, 0, stream>>>(ws, c2_w, c2_b, sc_w, sc_b, out);
}

// Round 9
// 241.787 us; speedup vs baseline: 1.3733x; 1.3733x over previous
//
#include <hip/hip_runtime.h>
#include <hip/hip_bf16.h>

using bf16 = __hip_bfloat16;

#define DI __device__ __forceinline__

typedef __attribute__((ext_vector_type(8))) short short8;
typedef __attribute__((ext_vector_type(8))) unsigned short u16x8;
typedef __attribute__((ext_vector_type(4))) unsigned short u16x4;
typedef __attribute__((ext_vector_type(4))) float f32x4;

#define MFMA_BF16 __builtin_amdgcn_mfma_f32_16x16x32_bf16

DI float leaky(float x) { return x > 0.f ? x : 0.1f * x; }

// bf16 split helpers (RNE). x = hi + lo to ~2^-16 relative.
DI unsigned short b16(float x) {
  union { float f; unsigned u; } v; v.f = x;
  unsigned r = v.u + 0x7FFFu + ((v.u >> 16) & 1u);
  return (unsigned short)(r >> 16);
}
DI float fromb16(unsigned short h) {
  union { unsigned u; float f; } v; v.u = ((unsigned)h) << 16; return v.f;
}

// Problem constants: B=2, C=64, H=64, W=64, N=4096. Inputs fp32 (R3/R4).
// NOTE R13: hipLaunchCooperativeKernel fails silently under graph capture here.
// Precision ladder (validated): Q/K split bf16, P hi-only, V hi-only in PV,
// L via ones-row MFMA. R2: swapped QK^T -> lane owns one pixel.
// ATTN LESSONS (R5-R7): 8-wave K-split loses; launch_bounds reg-pinning
// spills; V-direct-from-global loses. R4 attn (71.7us) is the local optimum.
// R8 LESSON: compiler does NOT scalarize uniform global weight reads ->
// per-lane VMEM with vmcnt stalls (coordconv 82.7us, VALUBusy 33%). Weights
// belong in LDS (broadcast ds_read, no conflicts).
// R9: R4 exact + 2 output rows per wave in convs: weight ds_read per output
// row halves (144->72 b128/wave), shfl/ch/row 6->4 (shared halo rows),
// loads/row 48->32. Per-output-row FMA order identical to R4 (bit-exact).
static constexpr int N_ = 4096;
static constexpr size_t CN = 262144;
static constexpr size_t BCN = 524288;

// ---- Workspace layout (float indices) ----
static constexpr size_t XG_OFF = 137104;
static constexpr size_t GG_OFF = XG_OFF + BCN;
static constexpr size_t QX_OFF = GG_OFF + BCN;
static constexpr size_t KX_OFF = QX_OFF + BCN;
static constexpr size_t VX_OFF = KX_OFF + BCN;
static constexpr size_t QG_OFF = VX_OFF + BCN;
static constexpr size_t KG_OFF = QG_OFF + BCN;
static constexpr size_t P1X_OFF = KG_OFF + BCN;
static constexpr size_t P1G_OFF = P1X_OFF + BCN;
static constexpr size_t ML_OFF  = P1G_OFF + BCN;
static constexpr size_t MLL_OFF = ML_OFF + 32768;
static constexpr size_t CA_OFF = ML_OFF;   // 256 floats; consumed by coordconv before attn writes ML
static constexpr size_t OB_OFF = QX_OFF;
static constexpr size_t UB_OFF = KX_OFF;
static constexpr size_t GO_OFF = GG_OFF;
static constexpr size_t QXH_U = QX_OFF * 2, QXL_U = QXH_U + BCN;
static constexpr size_t KXH_U = KX_OFF * 2, KXL_U = KXH_U + BCN;
static constexpr size_t VXH_U = VX_OFF * 2;
static constexpr size_t QGH_U = QG_OFF * 2, QGL_U = QGH_U + BCN;
static constexpr size_t KGH_U = KG_OFF * 2, KGL_U = KGH_U + BCN;
// Peak 19.7 MB (validated R6-R14)

// ---------------- K0: channel-attention scales (256 = src*128 + b*64 + ch) ----------------
__global__ __launch_bounds__(64) void k_ca(const float* __restrict__ x,
                                           const float* __restrict__ g,
                                           const float* __restrict__ lw_p,
                                           const float* __restrict__ lb_p,
                                           float* __restrict__ ws) {
  int blk = blockIdx.x;
  int ch = blk & 63; blk >>= 6;
  int b  = blk & 1;  blk >>= 1;
  int src = blk;
  const float* in = (src ? g : x) + ((size_t)(b * 64 + ch)) * N_;
  int t = threadIdx.x;
  float s = 0.f;
#pragma unroll
  for (int i = 0; i < 16; ++i) {
    float4 v = *reinterpret_cast<const float4*>(in + i * 256 + t * 4);
    s += (v.x + v.y) + (v.z + v.w);
  }
#pragma unroll
  for (int d = 1; d < 64; d <<= 1) s += __shfl_xor(s, d, 64);
  if (t == 0) {
    float p = s * (1.f / 4096.f);
    float lwv = lw_p[0], lbv = lb_p[0];
    float h = leaky(lwv * p + lbv);
    ws[CA_OFF + (src * 2 + b) * 64 + ch] = 1.f / (1.f + expf(-(lwv * h + lbv)));
  }
}

// ---------------- K1: coord-conv 3x3, channel-split, 2 rows/wave ----------------
__global__ __launch_bounds__(256) void k_coordconv(const float* __restrict__ x,
                                                   const float* __restrict__ g,
                                                   const float* __restrict__ cw,
                                                   float* __restrict__ ws) {
  int blk = blockIdx.x;  // 2048 = src*1024 + b*512 + og*32 + rt
  int rt = blk & 31; blk >>= 5;
  int og  = blk & 15; blk >>= 4;
  int b   = blk & 1;  blk >>= 1;
  int src = blk;
  int o0 = og * 4;
  int row0 = rt * 2;
  const float* in = src ? g : x;
  float* outp = ws + (src ? GG_OFF : XG_OFF);
  __shared__ __align__(16) float4 wl4[594];   // [ch*9+tap] -> 4 oc
  __shared__ float part[4][4][128];
  int t = threadIdx.x;
  int wv = t >> 6, px = t & 63;
  {
    float* wlf = (float*)wl4;
    for (int idx = t; idx < 2376; idx += 256)
      wlf[idx] = cw[(size_t)(o0 + (idx & 3)) * 594 + (idx >> 2)];
  }
  // input rows row0-1 .. row0+2 (k = 0..3)
  float mask[4]; int rcl[4];
#pragma unroll
  for (int k = 0; k < 4; ++k) {
    int ri = row0 - 1 + k;
    mask[k] = (ri >= 0 && ri < 64) ? 1.f : 0.f;
    rcl[k] = ri < 0 ? 0 : (ri > 63 ? 63 : ri);
  }
  int c0 = wv * 16;
  const float* base = in + ((size_t)(b * 64 + c0)) * N_ + px;
  float r[4][16];
#pragma unroll
  for (int i = 0; i < 16; ++i)
#pragma unroll
    for (int k = 0; k < 4; ++k)
      r[k][i] = base[(size_t)i * N_ + (size_t)rcl[k] * 64] * mask[k];
  float acc[2][4] = {};
  auto tap = [&](int ch, float v0, float v1, float v2, float v3) {
    float v[4] = {v0, v1, v2, v3};
    float lf[4], rg[4];
#pragma unroll
    for (int k = 0; k < 4; ++k) {
      lf[k] = __shfl_up(v[k], 1, 64);   if (px == 0)  lf[k] = 0.f;
      rg[k] = __shfl_down(v[k], 1, 64); if (px == 63) rg[k] = 0.f;
    }
#pragma unroll
    for (int ky = 0; ky < 3; ++ky) {
      float4 w0 = wl4[ch * 9 + ky * 3 + 0];
      float4 w1 = wl4[ch * 9 + ky * 3 + 1];
      float4 w2 = wl4[ch * 9 + ky * 3 + 2];
#pragma unroll
      for (int j = 0; j < 2; ++j) {
        int k = j + ky;
        acc[j][0] = fmaf(w0.x, lf[k], fmaf(w1.x, v[k], fmaf(w2.x, rg[k], acc[j][0])));
        acc[j][1] = fmaf(w0.y, lf[k], fmaf(w1.y, v[k], fmaf(w2.y, rg[k], acc[j][1])));
        acc[j][2] = fmaf(w0.z, lf[k], fmaf(w1.z, v[k], fmaf(w2.z, rg[k], acc[j][2])));
        acc[j][3] = fmaf(w0.w, lf[k], fmaf(w1.w, v[k], fmaf(w2.w, rg[k], acc[j][3])));
      }
    }
  };
  __syncthreads();   // weights ready
#pragma unroll
  for (int i = 0; i < 16; ++i) tap(c0 + i, r[0][i], r[1][i], r[2][i], r[3][i]);
  if (wv == 3) {
    // ch 64: xx varies along px (zero-padded rows/cols like real channels)
    float xx = (float)px * (2.f / 63.f) - 1.f;
    tap(64, mask[0] * xx, mask[1] * xx, mask[2] * xx, mask[3] * xx);
    // ch 65: yy constant along px, varies by row
    float y0 = mask[0] * ((float)(row0 - 1) * (2.f / 63.f) - 1.f);
    float y1 = mask[1] * ((float)(row0 + 0) * (2.f / 63.f) - 1.f);
    float y2 = mask[2] * ((float)(row0 + 1) * (2.f / 63.f) - 1.f);
    float y3 = mask[3] * ((float)(row0 + 2) * (2.f / 63.f) - 1.f);
    tap(65, y0, y1, y2, y3);
  }
#pragma unroll
  for (int j = 0; j < 2; ++j)
#pragma unroll
    for (int oo = 0; oo < 4; ++oo) part[wv][oo][j * 64 + px] = acc[j][oo];
  __syncthreads();
  int oc = t >> 6;
  float cav = ws[CA_OFF + (src * 2 + b) * 64 + o0 + oc];
#pragma unroll
  for (int j = 0; j < 2; ++j) {
    int jp = j * 64 + px;
    float s = (part[0][oc][jp] + part[1][oc][jp]) + (part[2][oc][jp] + part[3][oc][jp]);
    outp[((size_t)(b * 64 + o0 + oc)) * N_ + (size_t)(row0 + j) * 64 + px] = s * cav;
  }
}

// ---------------- K2: 1x1 projections; Q/K pre-split hi/lo, V hi-only transposed ----------------
__global__ __launch_bounds__(256) void k_proj(float* __restrict__ ws,
                                              const float* __restrict__ xqw, const float* __restrict__ xqb,
                                              const float* __restrict__ xkw, const float* __restrict__ xkb,
                                              const float* __restrict__ xvw, const float* __restrict__ xvb,
                                              const float* __restrict__ gqw, const float* __restrict__ gqb,
                                              const float* __restrict__ gkw, const float* __restrict__ gkb) {
  int blk = blockIdx.x;  // 5 * 2 * 64
  int pt = blk & 63; blk >>= 6;
  int b  = blk & 1;  blk >>= 1;
  int which = blk;
  size_t in_o;
  const float *wp, *bp;
  size_t hU = 0, lU = 0;
  if (which == 0)      { in_o = XG_OFF; wp = xqw; bp = xqb; hU = QXH_U; lU = QXL_U; }
  else if (which == 1) { in_o = XG_OFF; wp = xkw; bp = xkb; hU = KXH_U; lU = KXL_U; }
  else if (which == 2) { in_o = XG_OFF; wp = xvw; bp = xvb; }
  else if (which == 3) { in_o = GG_OFF; wp = gqw; bp = gqb; hU = QGH_U; lU = QGL_U; }
  else                 { in_o = GG_OFF; wp = gkw; bp = gkb; hU = KGH_U; lU = KGL_U; }

  __shared__ float tile[64 * 64];
  __shared__ float wl[64 * 65];
  __shared__ float bl[64];
  unsigned short* us = (unsigned short*)ws;
  int t = threadIdx.x;
  int pb = pt * 64;
  const float* in0 = ws + in_o + (size_t)b * CN + pb;
  for (int c0 = (t >> 6); c0 < 64; c0 += 4)
    tile[c0 * 64 + (t & 63)] = in0[(size_t)c0 * N_ + (t & 63)];
  for (int idx = t; idx < 4096; idx += 256)
    wl[(idx >> 6) * 65 + (idx & 63)] = wp[idx];
  if (t < 64) bl[t] = bp[t];
  __syncthreads();
  int o = t & 63, grp = t >> 6;
  const float* wr = &wl[o * 65];
  float acc[16];
  float bv = bl[o];
#pragma unroll
  for (int j = 0; j < 16; ++j) acc[j] = bv;
  for (int c = 0; c < 64; ++c) {
    float wv = wr[c];
    const float4* tb = reinterpret_cast<const float4*>(&tile[c * 64 + grp * 16]);
    float4 t0 = tb[0], t1 = tb[1], t2 = tb[2], t3 = tb[3];
    acc[0] = fmaf(wv, t0.x, acc[0]);   acc[1] = fmaf(wv, t0.y, acc[1]);
    acc[2] = fmaf(wv, t0.z, acc[2]);   acc[3] = fmaf(wv, t0.w, acc[3]);
    acc[4] = fmaf(wv, t1.x, acc[4]);   acc[5] = fmaf(wv, t1.y, acc[5]);
    acc[6] = fmaf(wv, t1.z, acc[6]);   acc[7] = fmaf(wv, t1.w, acc[7]);
    acc[8] = fmaf(wv, t2.x, acc[8]);   acc[9] = fmaf(wv, t2.y, acc[9]);
    acc[10] = fmaf(wv, t2.z, acc[10]); acc[11] = fmaf(wv, t2.w, acc[11]);
    acc[12] = fmaf(wv, t3.x, acc[12]); acc[13] = fmaf(wv, t3.y, acc[13]);
    acc[14] = fmaf(wv, t3.z, acc[14]); acc[15] = fmaf(wv, t3.w, acc[15]);
  }
  if (which != 2) {
#pragma unroll
    for (int j = 0; j < 16; ++j) {
      size_t idx = ((size_t)b * N_ + pb + grp * 16 + j) * 64 + o;
      unsigned short hi = b16(acc[j]);
      us[hU + idx] = hi;
      us[lU + idx] = b16(acc[j] - fromb16(hi));
    }
  } else {
    __syncthreads();
    float* ot = wl;
#pragma unroll
    for (int j = 0; j < 16; ++j) ot[o * 65 + grp * 16 + j] = acc[j];
    __syncthreads();
    int o2 = t >> 2;
#pragma unroll
    for (int e = 0; e < 4; ++e) {
      int px = (t & 3) * 16 + e * 4;
      u16x4 hv;
#pragma unroll
      for (int q = 0; q < 4; ++q) hv[q] = b16(ot[o2 * 65 + px + q]);
      size_t idx = ((size_t)(b * 64 + o2)) * N_ + pb + px;
      *reinterpret_cast<u16x4*>(&us[VXH_U + idx]) = hv;
    }
  }
}

// ---------------- K3: MFMA flash attention (R4 exact: Vth LDS dbuf, scalar P, per-lane softmax) ----------------
__global__ __launch_bounds__(256) void k_attn(float* __restrict__ ws) {
  unsigned short* us = (unsigned short*)ws;
  int blk = blockIdx.x;
  int half = blk & 1; blk >>= 1;
  int qt = blk & 63;  blk >>= 6;
  int b  = blk & 1;   blk >>= 1;
  int at = blk;
  const unsigned short* QH = us + (at ? QGH_U : QXH_U);
  const unsigned short* QL = us + (at ? QGL_U : QXL_U);
  const unsigned short* KHg = us + (at ? KGH_U : KXH_U);
  const unsigned short* KLg = us + (at ? KGL_U : KXL_U);
  const unsigned short* VHg = us + VXH_U;
  float* Pg = ws + (at ? (half ? P1G_OFF : GG_OFF) : (half ? P1X_OFF : XG_OFF))
            + (size_t)b * CN + qt * 64;

  __shared__ unsigned short Kh[2][4096], Kl[2][4096], Vth[2][4096], Ph[4096];

  int t = threadIdx.x;
  int w = t >> 6, lane = t & 63, quad = lane >> 4, l15 = lane & 15;
  int swz = l15 & 7;

  short8 qh[2], ql[2];
  {
    size_t qbase = ((size_t)b * N_ + qt * 64 + 16 * w + l15) * 64;
#pragma unroll
    for (int ks = 0; ks < 2; ++ks) {
      qh[ks] = *reinterpret_cast<const short8*>(&QH[qbase + ks * 32 + quad * 8]);
      ql[ks] = *reinterpret_cast<const short8*>(&QL[qbase + ks * 32 + quad * 8]);
    }
  }

  short8 ones;
#pragma unroll
  for (int j = 0; j < 8; ++j) ones[j] = (short)0x3F80;  // bf16 1.0

  int mt0 = half * 32, mt1 = half * 32 + 32;

  u16x8 rkh[2], rkl[2], rvh[2];
  size_t ko = ((size_t)b * N_ + (size_t)mt0 * 64 + (t >> 3)) * 64 + (size_t)(t & 7) * 8;
  size_t vo = ((size_t)(b * 64) + (t >> 3)) * N_ + (size_t)mt0 * 64 + (size_t)(t & 7) * 8;
  auto prefetch = [&]() {
    rkh[0] = *reinterpret_cast<const u16x8*>(&KHg[ko]);
    rkl[0] = *reinterpret_cast<const u16x8*>(&KLg[ko]);
    rkh[1] = *reinterpret_cast<const u16x8*>(&KHg[ko + 2048]);
    rkl[1] = *reinterpret_cast<const u16x8*>(&KLg[ko + 2048]);
    rvh[0] = *reinterpret_cast<const u16x8*>(&VHg[vo]);
    rvh[1] = *reinterpret_cast<const u16x8*>(&VHg[vo + (size_t)32 * N_]);
    ko += 4096; vo += 64;
  };
  int wr0 = t >> 3, wch = t & 7;
  int woff = wr0 * 64 + ((wch ^ (wr0 & 7)) << 3);
  auto writebuf = [&](int par) {
    *reinterpret_cast<u16x8*>(&Kh[par][woff]) = rkh[0];
    *reinterpret_cast<u16x8*>(&Kl[par][woff]) = rkl[0];
    *reinterpret_cast<u16x8*>(&Vth[par][woff]) = rvh[0];
    *reinterpret_cast<u16x8*>(&Kh[par][woff + 2048]) = rkh[1];
    *reinterpret_cast<u16x8*>(&Kl[par][woff + 2048]) = rkl[1];
    *reinterpret_cast<u16x8*>(&Vth[par][woff + 2048]) = rvh[1];
  };

  f32x4 Oa[4] = {{0.f, 0.f, 0.f, 0.f}, {0.f, 0.f, 0.f, 0.f},
                 {0.f, 0.f, 0.f, 0.f}, {0.f, 0.f, 0.f, 0.f}};
  f32x4 La = {0.f, 0.f, 0.f, 0.f};   // L in element 0 (ones-row MFMA; rows identical)
  float M = -1e30f;                  // per-lane: pixel n = 16w + l15

  int phb = (16 * w + l15) * 64;
  int mh = quad >> 1, mlw = (quad & 1) * 4;

  prefetch();
  writebuf(0);
  __syncthreads();
  for (int mt = mt0; mt < mt1; ++mt) {
    int pb = (mt - mt0) & 1;
    if (mt + 1 < mt1) prefetch();  // global latency overlaps tile compute

    // S^T[m][n]: m = ms*16 + quad*4 + reg, n = 16w + l15 (swapped operands)
    f32x4 S[4];
    __builtin_amdgcn_s_setprio(1);
#pragma unroll
    for (int ms = 0; ms < 4; ++ms) {
      f32x4 a0 = {0.f, 0.f, 0.f, 0.f}, a1 = {0.f, 0.f, 0.f, 0.f};
      int row = ms * 16 + l15;
#pragma unroll
      for (int ks = 0; ks < 2; ++ks) {
        int off = row * 64 + (((ks * 4 + quad) ^ swz) << 3);
        short8 khf = *reinterpret_cast<const short8*>(&Kh[pb][off]);
        short8 klf = *reinterpret_cast<const short8*>(&Kl[pb][off]);
        f32x4& a = ks ? a1 : a0;
        a = MFMA_BF16(khf, ql[ks], a, 0, 0, 0);
        a = MFMA_BF16(klf, qh[ks], a, 0, 0, 0);
        a = MFMA_BF16(khf, qh[ks], a, 0, 0, 0);
      }
      S[ms] = a0 + a1;
    }
    __builtin_amdgcn_s_setprio(0);

    // in-lane max over 16 values + 2-step cross-quad butterfly
    float m0 = fmaxf(fmaxf(S[0][0], S[0][1]), fmaxf(S[0][2], S[0][3]));
    float m1 = fmaxf(fmaxf(S[1][0], S[1][1]), fmaxf(S[1][2], S[1][3]));
    float m2 = fmaxf(fmaxf(S[2][0], S[2][1]), fmaxf(S[2][2], S[2][3]));
    float m3 = fmaxf(fmaxf(S[3][0], S[3][1]), fmaxf(S[3][2], S[3][3]));
    float tm = fmaxf(fmaxf(m0, m1), fmaxf(m2, m3));
    tm = fmaxf(tm, __shfl_xor(tm, 16, 64));
    tm = fmaxf(tm, __shfl_xor(tm, 32, 64));
    float mn = fmaxf(M, tm);
    float al = __expf(M - mn);
    M = mn;
#pragma unroll
    for (int ms = 0; ms < 4; ++ms) {
      int goff = phb + ((((ms << 1) + mh) ^ swz) << 3) + mlw;
#pragma unroll
      for (int r = 0; r < 4; ++r) {
        float p = __expf(S[ms][r] - mn);
        Ph[goff + r] = b16(p);   // wave-private rows -> no barrier needed
      }
    }
#pragma unroll
    for (int cs = 0; cs < 4; ++cs) {
      Oa[cs][0] *= al; Oa[cs][1] *= al; Oa[cs][2] *= al; Oa[cs][3] *= al;
    }
    La[0] *= al;

    // O^T += V^T P^T, V hi-only: 10 MFMAs (incl. 2 ones-row for L), 10 ds_reads/tile
    __builtin_amdgcn_s_setprio(1);
#pragma unroll
    for (int ks = 0; ks < 2; ++ks) {
      int poff = phb + (((ks * 4 + quad) ^ swz) << 3);
      short8 phf = *reinterpret_cast<const short8*>(&Ph[poff]);
      La = MFMA_BF16(ones, phf, La, 0, 0, 0);   // row-sums of P == L partials
#pragma unroll
      for (int cs = 0; cs < 4; ++cs) {
        int voff = (cs * 16 + l15) * 64 + (((ks * 4 + quad) ^ swz) << 3);
        short8 vhf = *reinterpret_cast<const short8*>(&Vth[pb][voff]);
        Oa[cs] = MFMA_BF16(vhf, phf, Oa[cs], 0, 0, 0);
      }
    }
    __builtin_amdgcn_s_setprio(0);

    if (mt + 1 < mt1) writebuf(pb ^ 1);  // fenced by previous iteration's barrier
    __syncthreads();
  }

#pragma unroll
  for (int cs = 0; cs < 4; ++cs) {
#pragma unroll
    for (int r = 0; r < 4; ++r) {
      int c = cs * 16 + quad * 4 + r;
      Pg[(size_t)c * N_ + 16 * w + l15] = Oa[cs][r];
    }
  }
  if (quad == 0) {
    int mlb = ((at * 2 + half) * 2 + b) * 4096 + qt * 64 + 16 * w + l15;
    ws[ML_OFF + mlb] = M;
    ws[MLL_OFF + mlb] = La[0];   // La col = pixel 16w+l15, rows identical
  }
}

// ---------------- K4: merge halves + combine ----------------
__global__ __launch_bounds__(256) void k_merge(float* __restrict__ ws,
                                               const float* __restrict__ gm_p,
                                               const float* __restrict__ al_p) {
  size_t i4 = (size_t)blockIdx.x * 256 + threadIdx.x;
  size_t i = i4 * 4;
  int n = (int)(i & 4095);
  int b = (int)(i >> 18);
  float gm = gm_p[0], al = al_p[0];
  float4 p0x = *reinterpret_cast<const float4*>(ws + XG_OFF + i);
  float4 p1x = *reinterpret_cast<const float4*>(ws + P1X_OFF + i);
  float4 p0g = *reinterpret_cast<const float4*>(ws + GG_OFF + i);
  float4 p1g = *reinterpret_cast<const float4*>(ws + P1G_OFF + i);
  float4 M0x = *reinterpret_cast<const float4*>(ws + ML_OFF  + (0 + b) * 4096 + n);
  float4 L0x = *reinterpret_cast<const float4*>(ws + MLL_OFF + (0 + b) * 4096 + n);
  float4 M1x = *reinterpret_cast<const float4*>(ws + ML_OFF  + (2 + b) * 4096 + n);
  float4 L1x = *reinterpret_cast<const float4*>(ws + MLL_OFF + (2 + b) * 4096 + n);
  float4 M0g = *reinterpret_cast<const float4*>(ws + ML_OFF  + (4 + b) * 4096 + n);
  float4 L0g = *reinterpret_cast<const float4*>(ws + MLL_OFF + (4 + b) * 4096 + n);
  float4 M1g = *reinterpret_cast<const float4*>(ws + ML_OFF  + (6 + b) * 4096 + n);
  float4 L1g = *reinterpret_cast<const float4*>(ws + MLL_OFF + (6 + b) * 4096 + n);
  const float* p0xv = (const float*)&p0x; const float* p1xv = (const float*)&p1x;
  const float* p0gv = (const float*)&p0g; const float* p1gv = (const float*)&p1g;
  const float* m0xv = (const float*)&M0x; const float* l0xv = (const float*)&L0x;
  const float* m1xv = (const float*)&M1x; const float* l1xv = (const float*)&L1x;
  const float* m0gv = (const float*)&M0g; const float* l0gv = (const float*)&L0g;
  const float* m1gv = (const float*)&M1g; const float* l1gv = (const float*)&L1g;
  float4 go, ob;
  float* gov = (float*)&go; float* obv = (float*)&ob;
#pragma unroll
  for (int l = 0; l < 4; ++l) {
    float mx = fmaxf(m0xv[l], m1xv[l]);
    float w0 = __expf(m0xv[l] - mx), w1 = __expf(m1xv[l] - mx);
    float xc = (p0xv[l] * w0 + p1xv[l] * w1) / (l0xv[l] * w0 + l1xv[l] * w1);
    float mg = fmaxf(m0gv[l], m1gv[l]);
    float v0 = __expf(m0gv[l] - mg), v1 = __expf(m1gv[l] - mg);
    float gc = (p0gv[l] * v0 + p1gv[l] * v1) / (l0gv[l] * v0 + l1gv[l] * v1);
    gov[l] = gc;
    obv[l] = gm * xc + al * gc;
  }
  *reinterpret_cast<float4*>(ws + GG_OFF + i) = go;  // GO
  *reinterpret_cast<float4*>(ws + QX_OFF + i) = ob;  // OB
}

// ---------------- K5: u = leaky(conv3x3(leaky(out), c1)), channel-split, 2 rows/wave ----------------
__global__ __launch_bounds__(256) void k_conv1(float* __restrict__ ws,
                                               const float* __restrict__ c1w,
                                               const float* __restrict__ c1b) {
  int blk = blockIdx.x;  // 1024 = b*512 + og*32 + rt
  int rt = blk & 31; blk >>= 5;
  int og  = blk & 15; blk >>= 4;
  int b   = blk;
  int o0 = og * 4;
  int row0 = rt * 2;
  __shared__ __align__(16) float4 wl4[576];
  __shared__ float part[4][4][128];
  int t = threadIdx.x;
  int wv = t >> 6, px = t & 63;
  {
    float* wlf = (float*)wl4;
    for (int idx = t; idx < 2304; idx += 256)
      wlf[idx] = c1w[(size_t)(o0 + (idx & 3)) * 576 + (idx >> 2)];
  }
  float mask[4]; int rcl[4];
#pragma unroll
  for (int k = 0; k < 4; ++k) {
    int ri = row0 - 1 + k;
    mask[k] = (ri >= 0 && ri < 64) ? 1.f : 0.f;
    rcl[k] = ri < 0 ? 0 : (ri > 63 ? 63 : ri);
  }
  int c0 = wv * 16;
  const float* base = ws + OB_OFF + (size_t)b * CN + (size_t)c0 * N_ + px;
  float r[4][16];
#pragma unroll
  for (int i = 0; i < 16; ++i)
#pragma unroll
    for (int k = 0; k < 4; ++k)
      r[k][i] = leaky(base[(size_t)i * N_ + (size_t)rcl[k] * 64]) * mask[k];
  float acc[2][4] = {};
  auto tap = [&](int ch, float v0, float v1, float v2, float v3) {
    float v[4] = {v0, v1, v2, v3};
    float lf[4], rg[4];
#pragma unroll
    for (int k = 0; k < 4; ++k) {
      lf[k] = __shfl_up(v[k], 1, 64);   if (px == 0)  lf[k] = 0.f;
      rg[k] = __shfl_down(v[k], 1, 64); if (px == 63) rg[k] = 0.f;
    }
#pragma unroll
    for (int ky = 0; ky < 3; ++ky) {
      float4 w0 = wl4[ch * 9 + ky * 3 + 0];
      float4 w1 = wl4[ch * 9 + ky * 3 + 1];
      float4 w2 = wl4[ch * 9 + ky * 3 + 2];
#pragma unroll
      for (int j = 0; j < 2; ++j) {
        int k = j + ky;
        acc[j][0] = fmaf(w0.x, lf[k], fmaf(w1.x, v[k], fmaf(w2.x, rg[k], acc[j][0])));
        acc[j][1] = fmaf(w0.y, lf[k], fmaf(w1.y, v[k], fmaf(w2.y, rg[k], acc[j][1])));
        acc[j][2] = fmaf(w0.z, lf[k], fmaf(w1.z, v[k], fmaf(w2.z, rg[k], acc[j][2])));
        acc[j][3] = fmaf(w0.w, lf[k], fmaf(w1.w, v[k], fmaf(w2.w, rg[k], acc[j][3])));
      }
    }
  };
  __syncthreads();
#pragma unroll
  for (int i = 0; i < 16; ++i) tap(c0 + i, r[0][i], r[1][i], r[2][i], r[3][i]);
#pragma unroll
  for (int j = 0; j < 2; ++j)
#pragma unroll
    for (int oo = 0; oo < 4; ++oo) part[wv][oo][j * 64 + px] = acc[j][oo];
  __syncthreads();
  int oc = t >> 6;
  float bb = c1b[o0 + oc];
  float* ub = ws + UB_OFF + (size_t)b * CN;
#pragma unroll
  for (int j = 0; j < 2; ++j) {
    int jp = j * 64 + px;
    float s = (part[0][oc][jp] + part[1][oc][jp]) + (part[2][oc][jp] + part[3][oc][jp]);
    ub[(size_t)(o0 + oc) * N_ + (size_t)(row0 + j) * 64 + px] = leaky(s + bb);
  }
}

// ---------------- K6: final, channel-split + fused sc dot, 2 rows/wave ----------------
__global__ __launch_bounds__(256) void k_final(const float* __restrict__ ws,
                                               const float* __restrict__ c2w,
                                               const float* __restrict__ c2b,
                                               const float* __restrict__ scw,
                                               const float* __restrict__ scb,
                                               float* __restrict__ out) {
  int blk = blockIdx.x;  // 1024 = b*512 + og*32 + rt
  int rt = blk & 31; blk >>= 5;
  int og  = blk & 15; blk >>= 4;
  int b   = blk;
  int o0 = og * 4;
  int row0 = rt * 2;
  __shared__ __align__(16) float4 wl4[576];
  __shared__ __align__(16) float4 scl4[64];
  __shared__ float part[4][4][128];
  __shared__ float part2[4][4][128];
  int t = threadIdx.x;
  int wv = t >> 6, px = t & 63;
  {
    float* wlf = (float*)wl4;
    for (int idx = t; idx < 2304; idx += 256)
      wlf[idx] = c2w[(size_t)(o0 + (idx & 3)) * 576 + (idx >> 2)];
    float* sclf = (float*)scl4;
    if (t < 256) {
      int idx = t;
      sclf[idx] = scw[(size_t)(o0 + (idx & 3)) * 64 + (idx >> 2)];
    }
  }
  float mask[4]; int rcl[4];
#pragma unroll
  for (int k = 0; k < 4; ++k) {
    int ri = row0 - 1 + k;
    mask[k] = (ri >= 0 && ri < 64) ? 1.f : 0.f;
    rcl[k] = ri < 0 ? 0 : (ri > 63 ? 63 : ri);
  }
  int c0 = wv * 16;
  const float* base = ws + UB_OFF + (size_t)b * CN + (size_t)c0 * N_ + px;
  const float* obb  = ws + OB_OFF + (size_t)b * CN + (size_t)c0 * N_ + px;
  float r[4][16], ob[2][16];
#pragma unroll
  for (int i = 0; i < 16; ++i) {
#pragma unroll
    for (int k = 0; k < 4; ++k)
      r[k][i] = base[(size_t)i * N_ + (size_t)rcl[k] * 64] * mask[k];
#pragma unroll
    for (int j = 0; j < 2; ++j)
      ob[j][i] = obb[(size_t)i * N_ + (size_t)(row0 + j) * 64];
  }
  float acc[2][4] = {};
  float scp[2][4] = {};
  auto tap = [&](int ch, float v0, float v1, float v2, float v3) {
    float v[4] = {v0, v1, v2, v3};
    float lf[4], rg[4];
#pragma unroll
    for (int k = 0; k < 4; ++k) {
      lf[k] = __shfl_up(v[k], 1, 64);   if (px == 0)  lf[k] = 0.f;
      rg[k] = __shfl_down(v[k], 1, 64); if (px == 63) rg[k] = 0.f;
    }
#pragma unroll
    for (int ky = 0; ky < 3; ++ky) {
      float4 w0 = wl4[ch * 9 + ky * 3 + 0];
      float4 w1 = wl4[ch * 9 + ky * 3 + 1];
      float4 w2 = wl4[ch * 9 + ky * 3 + 2];
#pragma unroll
      for (int j = 0; j < 2; ++j) {
        int k = j + ky;
        acc[j][0] = fmaf(w0.x, lf[k], fmaf(w1.x, v[k], fmaf(w2.x, rg[k], acc[j][0])));
        acc[j][1] = fmaf(w0.y, lf[k], fmaf(w1.y, v[k], fmaf(w2.y, rg[k], acc[j][1])));
        acc[j][2] = fmaf(w0.z, lf[k], fmaf(w1.z, v[k], fmaf(w2.z, rg[k], acc[j][2])));
        acc[j][3] = fmaf(w0.w, lf[k], fmaf(w1.w, v[k], fmaf(w2.w, rg[k], acc[j][3])));
      }
    }
  };
  __syncthreads();
#pragma unroll
  for (int i = 0; i < 16; ++i) {
    tap(c0 + i, r[0][i], r[1][i], r[2][i], r[3][i]);
    float4 s4 = scl4[c0 + i];
#pragma unroll
    for (int j = 0; j < 2; ++j) {
      scp[j][0] = fmaf(s4.x, ob[j][i], scp[j][0]);
      scp[j][1] = fmaf(s4.y, ob[j][i], scp[j][1]);
      scp[j][2] = fmaf(s4.z, ob[j][i], scp[j][2]);
      scp[j][3] = fmaf(s4.w, ob[j][i], scp[j][3]);
    }
  }
#pragma unroll
  for (int j = 0; j < 2; ++j)
#pragma unroll
    for (int oo = 0; oo < 4; ++oo) {
      part[wv][oo][j * 64 + px] = acc[j][oo];
      part2[wv][oo][j * 64 + px] = scp[j][oo];
    }
  __syncthreads();
  int oc = t >> 6;
  float c2bv = c2b[o0 + oc];
  float scbv = scb[o0 + oc];
  const float* go = ws + GO_OFF + (size_t)b * CN;
  float* ob_out = out + (size_t)b * CN;
#pragma unroll
  for (int j = 0; j < 2; ++j) {
    int jp = j * 64 + px;
    float s  = (part[0][oc][jp] + part[1][oc][jp]) + (part[2][oc][jp] + part[3][oc][jp]);
    float sc = (part2[0][oc][jp] + part2[1][oc][jp]) + (part2[2][oc][jp] + part2[3][oc][jp]);
    size_t pix = (size_t)(row0 + j) * 64 + px;
    float gvv = go[(size_t)(o0 + oc) * N_ + pix];
    ob_out[(size_t)(o0 + oc) * N_ + pix] = (s + c2bv) + (sc + scbv) * gvv;
  }
}

extern "C" void kernel_launch(void* const* d_in, const int* in_sizes, int n_in,
                              void* d_out, int out_size, void* d_ws, size_t ws_size,
                              hipStream_t stream) {
  const float* x     = (const float*)d_in[0];
  const float* guide = (const float*)d_in[1];
  const float* lin_w = (const float*)d_in[2];
  const float* lin_b = (const float*)d_in[3];
  const float* cw    = (const float*)d_in[4];
  const float* xq_w  = (const float*)d_in[5];
  const float* xq_b  = (const float*)d_in[6];
  const float* xk_w  = (const float*)d_in[7];
  const float* xk_b  = (const float*)d_in[8];
  const float* xv_w  = (const float*)d_in[9];
  const float* xv_b  = (const float*)d_in[10];
  const float* gq_w  = (const float*)d_in[11];
  const float* gq_b  = (const float*)d_in[12];
  const float* gk_w  = (const float*)d_in[13];
  const float* gk_b  = (const float*)d_in[14];
  const float* gamma = (const float*)d_in[15];
  const float* alpha = (const float*)d_in[16];
  const float* c1_w  = (const float*)d_in[17];
  const float* c1_b  = (const float*)d_in[18];
  const float* c2_w  = (const float*)d_in[19];
  const float* c2_b  = (const float*)d_in[20];
  const float* sc_w  = (const float*)d_in[21];
  const float* sc_b  = (const float*)d_in[22];
  float* out = (float*)d_out;
  float* ws = (float*)d_ws;

  k_ca<<<256, 64, 0, stream>>>(x, guide, lin_w, lin_b, ws);
  k_coordconv<<<2048, 256, 0, stream>>>(x, guide, cw, ws);
  k_proj<<<640, 256, 0, stream>>>(ws, xq_w, xq_b, xk_w, xk_b, xv_w, xv_b,
                                  gq_w, gq_b, gk_w, gk_b);
  k_attn<<<512, 256, 0, stream>>>(ws);
  k_merge<<<512, 256, 0, stream>>>(ws, gamma, alpha);
  k_conv1<<<1024, 256, 0, stream>>>(ws, c1_w, c1_b);
  k_final<<<1024, 256, 0, stream>>>(ws, c2_w, c2_b, sc_w, sc_b, out);
}

// Round 10
// 241.300 us; speedup vs baseline: 1.3761x; 1.0020x over previous
//
#include <hip/hip_runtime.h>
#include <hip/hip_bf16.h>

using bf16 = __hip_bfloat16;

#define DI __device__ __forceinline__

typedef __attribute__((ext_vector_type(8))) short short8;
typedef __attribute__((ext_vector_type(8))) unsigned short u16x8;
typedef __attribute__((ext_vector_type(4))) unsigned short u16x4;
typedef __attribute__((ext_vector_type(4))) float f32x4;

#define MFMA_BF16 __builtin_amdgcn_mfma_f32_16x16x32_bf16

DI float leaky(float x) { return x > 0.f ? x : 0.1f * x; }

// bf16 split helpers (RNE). x = hi + lo to ~2^-16 relative.
DI unsigned short b16(float x) {
  union { float f; unsigned u; } v; v.f = x;
  unsigned r = v.u + 0x7FFFu + ((v.u >> 16) & 1u);
  return (unsigned short)(r >> 16);
}
DI float fromb16(unsigned short h) {
  union { unsigned u; float f; } v; v.u = ((unsigned)h) << 16; return v.f;
}

// Problem constants: B=2, C=64, H=64, W=64, N=4096. Inputs fp32 (R3/R4).
// NOTE R13: hipLaunchCooperativeKernel fails silently under graph capture here.
// Precision ladder (validated): Q/K split bf16, P hi-only, V hi-only in PV,
// L via ones-row MFMA. R2: swapped QK^T -> lane owns one pixel.
// ATTN LESSONS (R5-R7): 8-wave K-split loses; launch_bounds reg-pinning
// spills; V-direct-from-global loses. R4 attn is the local optimum (66us in
// the R9 launch mix) -> frozen.
// R8 LESSON: compiler does NOT scalarize uniform global reads -> weights
// belong in LDS. R9: convs 2 rows/wave (weight ds_read/row halved) -> 241.8.
// R10: proj was LDS-issue-bound (5 LDS instr : 16 FMA; each activation float
// feeds ONE FMA). Re-tile thread output to 4o x 4px: per c-iter exactly
// 2 ds_read_b128 (activation float4 + weight float4) : 16 FMA. Weights
// pre-transposed to [c][o] in k_ca (WT region, consumed before attn writes
// ML). V store becomes direct u16x4 in V^T layout -> transpose epilogue
// (+2 barriers) deleted. Per-output FMA order unchanged -> bit-identical.
static constexpr int N_ = 4096;
static constexpr size_t CN = 262144;
static constexpr size_t BCN = 524288;

// ---- Workspace layout (float indices) ----
static constexpr size_t XG_OFF = 137104;
static constexpr size_t GG_OFF = XG_OFF + BCN;
static constexpr size_t QX_OFF = GG_OFF + BCN;
static constexpr size_t KX_OFF = QX_OFF + BCN;
static constexpr size_t VX_OFF = KX_OFF + BCN;
static constexpr size_t QG_OFF = VX_OFF + BCN;
static constexpr size_t KG_OFF = QG_OFF + BCN;
static constexpr size_t P1X_OFF = KG_OFF + BCN;
static constexpr size_t P1G_OFF = P1X_OFF + BCN;
static constexpr size_t ML_OFF  = P1G_OFF + BCN;
static constexpr size_t MLL_OFF = ML_OFF + 32768;
static constexpr size_t CA_OFF = ML_OFF;        // 256 floats; consumed by coordconv before attn writes ML
static constexpr size_t WT_OFF = ML_OFF + 256;  // 5*4096 transposed proj weights; consumed by proj before attn
static constexpr size_t OB_OFF = QX_OFF;
static constexpr size_t UB_OFF = KX_OFF;
static constexpr size_t GO_OFF = GG_OFF;
static constexpr size_t QXH_U = QX_OFF * 2, QXL_U = QXH_U + BCN;
static constexpr size_t KXH_U = KX_OFF * 2, KXL_U = KXH_U + BCN;
static constexpr size_t VXH_U = VX_OFF * 2;
static constexpr size_t QGH_U = QG_OFF * 2, QGL_U = QGH_U + BCN;
static constexpr size_t KGH_U = KG_OFF * 2, KGL_U = KGH_U + BCN;
// Peak 19.7 MB (validated R6-R14)

// ---------------- K0: channel-attention scales + proj weight transpose ----------------
__global__ __launch_bounds__(64) void k_ca(const float* __restrict__ x,
                                           const float* __restrict__ g,
                                           const float* __restrict__ lw_p,
                                           const float* __restrict__ lb_p,
                                           const float* __restrict__ xqw,
                                           const float* __restrict__ xkw,
                                           const float* __restrict__ xvw,
                                           const float* __restrict__ gqw,
                                           const float* __restrict__ gkw,
                                           float* __restrict__ ws) {
  int blk = blockIdx.x;
  int ch = blk & 63; blk >>= 6;
  int b  = blk & 1;  blk >>= 1;
  int src = blk;
  const float* in = (src ? g : x) + ((size_t)(b * 64 + ch)) * N_;
  int t = threadIdx.x;
  float s = 0.f;
#pragma unroll
  for (int i = 0; i < 16; ++i) {
    float4 v = *reinterpret_cast<const float4*>(in + i * 256 + t * 4);
    s += (v.x + v.y) + (v.z + v.w);
  }
#pragma unroll
  for (int d = 1; d < 64; d <<= 1) s += __shfl_xor(s, d, 64);
  if (t == 0) {
    float p = s * (1.f / 4096.f);
    float lwv = lw_p[0], lbv = lb_p[0];
    float h = leaky(lwv * p + lbv);
    ws[CA_OFF + (src * 2 + b) * 64 + ch] = 1.f / (1.f + expf(-(lwv * h + lbv)));
  }
  // transpose 5 proj weight mats (O x C -> C x O) into WT region (coalesced reads)
  int gid = blockIdx.x * 64 + t;
  for (int idx = gid; idx < 20480; idx += 16384) {
    int m = idx >> 12, e = idx & 4095;
    const float* wp = (m == 0) ? xqw : (m == 1) ? xkw : (m == 2) ? xvw : (m == 3) ? gqw : gkw;
    ws[WT_OFF + (m << 12) + ((e & 63) << 6) + (e >> 6)] = wp[e];
  }
}

// ---------------- K1: coord-conv 3x3, channel-split, 2 rows/wave ----------------
__global__ __launch_bounds__(256) void k_coordconv(const float* __restrict__ x,
                                                   const float* __restrict__ g,
                                                   const float* __restrict__ cw,
                                                   float* __restrict__ ws) {
  int blk = blockIdx.x;  // 2048 = src*1024 + b*512 + og*32 + rt
  int rt = blk & 31; blk >>= 5;
  int og  = blk & 15; blk >>= 4;
  int b   = blk & 1;  blk >>= 1;
  int src = blk;
  int o0 = og * 4;
  int row0 = rt * 2;
  const float* in = src ? g : x;
  float* outp = ws + (src ? GG_OFF : XG_OFF);
  __shared__ __align__(16) float4 wl4[594];   // [ch*9+tap] -> 4 oc
  __shared__ float part[4][4][128];
  int t = threadIdx.x;
  int wv = t >> 6, px = t & 63;
  {
    float* wlf = (float*)wl4;
    for (int idx = t; idx < 2376; idx += 256)
      wlf[idx] = cw[(size_t)(o0 + (idx & 3)) * 594 + (idx >> 2)];
  }
  // input rows row0-1 .. row0+2 (k = 0..3)
  float mask[4]; int rcl[4];
#pragma unroll
  for (int k = 0; k < 4; ++k) {
    int ri = row0 - 1 + k;
    mask[k] = (ri >= 0 && ri < 64) ? 1.f : 0.f;
    rcl[k] = ri < 0 ? 0 : (ri > 63 ? 63 : ri);
  }
  int c0 = wv * 16;
  const float* base = in + ((size_t)(b * 64 + c0)) * N_ + px;
  float r[4][16];
#pragma unroll
  for (int i = 0; i < 16; ++i)
#pragma unroll
    for (int k = 0; k < 4; ++k)
      r[k][i] = base[(size_t)i * N_ + (size_t)rcl[k] * 64] * mask[k];
  float acc[2][4] = {};
  auto tap = [&](int ch, float v0, float v1, float v2, float v3) {
    float v[4] = {v0, v1, v2, v3};
    float lf[4], rg[4];
#pragma unroll
    for (int k = 0; k < 4; ++k) {
      lf[k] = __shfl_up(v[k], 1, 64);   if (px == 0)  lf[k] = 0.f;
      rg[k] = __shfl_down(v[k], 1, 64); if (px == 63) rg[k] = 0.f;
    }
#pragma unroll
    for (int ky = 0; ky < 3; ++ky) {
      float4 w0 = wl4[ch * 9 + ky * 3 + 0];
      float4 w1 = wl4[ch * 9 + ky * 3 + 1];
      float4 w2 = wl4[ch * 9 + ky * 3 + 2];
#pragma unroll
      for (int j = 0; j < 2; ++j) {
        int k = j + ky;
        acc[j][0] = fmaf(w0.x, lf[k], fmaf(w1.x, v[k], fmaf(w2.x, rg[k], acc[j][0])));
        acc[j][1] = fmaf(w0.y, lf[k], fmaf(w1.y, v[k], fmaf(w2.y, rg[k], acc[j][1])));
        acc[j][2] = fmaf(w0.z, lf[k], fmaf(w1.z, v[k], fmaf(w2.z, rg[k], acc[j][2])));
        acc[j][3] = fmaf(w0.w, lf[k], fmaf(w1.w, v[k], fmaf(w2.w, rg[k], acc[j][3])));
      }
    }
  };
  __syncthreads();   // weights ready
#pragma unroll
  for (int i = 0; i < 16; ++i) tap(c0 + i, r[0][i], r[1][i], r[2][i], r[3][i]);
  if (wv == 3) {
    // ch 64: xx varies along px (zero-padded rows/cols like real channels)
    float xx = (float)px * (2.f / 63.f) - 1.f;
    tap(64, mask[0] * xx, mask[1] * xx, mask[2] * xx, mask[3] * xx);
    // ch 65: yy constant along px, varies by row
    float y0 = mask[0] * ((float)(row0 - 1) * (2.f / 63.f) - 1.f);
    float y1 = mask[1] * ((float)(row0 + 0) * (2.f / 63.f) - 1.f);
    float y2 = mask[2] * ((float)(row0 + 1) * (2.f / 63.f) - 1.f);
    float y3 = mask[3] * ((float)(row0 + 2) * (2.f / 63.f) - 1.f);
    tap(65, y0, y1, y2, y3);
  }
#pragma unroll
  for (int j = 0; j < 2; ++j)
#pragma unroll
    for (int oo = 0; oo < 4; ++oo) part[wv][oo][j * 64 + px] = acc[j][oo];
  __syncthreads();
  int oc = t >> 6;
  float cav = ws[CA_OFF + (src * 2 + b) * 64 + o0 + oc];
#pragma unroll
  for (int j = 0; j < 2; ++j) {
    int jp = j * 64 + px;
    float s = (part[0][oc][jp] + part[1][oc][jp]) + (part[2][oc][jp] + part[3][oc][jp]);
    outp[((size_t)(b * 64 + o0 + oc)) * N_ + (size_t)(row0 + j) * 64 + px] = s * cav;
  }
}

// ---------------- K2: 1x1 projections; 4o x 4px per thread, transposed weights ----------------
__global__ __launch_bounds__(256) void k_proj(float* __restrict__ ws,
                                              const float* __restrict__ xqb,
                                              const float* __restrict__ xkb,
                                              const float* __restrict__ xvb,
                                              const float* __restrict__ gqb,
                                              const float* __restrict__ gkb) {
  int blk = blockIdx.x;  // 5 * 2 * 64
  int pt = blk & 63; blk >>= 6;
  int b  = blk & 1;  blk >>= 1;
  int which = blk;
  size_t in_o = (which <= 2) ? XG_OFF : GG_OFF;
  const float* bp = (which == 0) ? xqb : (which == 1) ? xkb : (which == 2) ? xvb
                   : (which == 3) ? gqb : gkb;
  size_t hU = 0, lU = 0;
  if (which == 0)      { hU = QXH_U; lU = QXL_U; }
  else if (which == 1) { hU = KXH_U; lU = KXL_U; }
  else if (which == 3) { hU = QGH_U; lU = QGL_U; }
  else if (which == 4) { hU = KGH_U; lU = KGL_U; }

  __shared__ __align__(16) float tile[4096];   // [c][px]
  __shared__ __align__(16) float wlT[4096];    // [c][o]
  __shared__ __align__(16) float bl[64];
  unsigned short* us = (unsigned short*)ws;
  int t = threadIdx.x;
  int pb = pt * 64;
  const float* in0 = ws + in_o + (size_t)b * CN + pb;
  for (int c0 = (t >> 6); c0 < 64; c0 += 4)
    tile[c0 * 64 + (t & 63)] = in0[(size_t)c0 * N_ + (t & 63)];
  const float* wtG = ws + WT_OFF + (size_t)which * 4096;
  for (int idx = t; idx < 4096; idx += 256)
    wlT[idx] = wtG[idx];
  if (t < 64) bl[t] = bp[t];
  __syncthreads();
  int o4 = (t & 15) * 4, p4 = (t >> 4) * 4;
  float4 bv4 = *reinterpret_cast<const float4*>(&bl[o4]);
  float acc[4][4];   // [p'][o']
#pragma unroll
  for (int p = 0; p < 4; ++p) {
    acc[p][0] = bv4.x; acc[p][1] = bv4.y; acc[p][2] = bv4.z; acc[p][3] = bv4.w;
  }
#pragma unroll 8
  for (int c = 0; c < 64; ++c) {
    float4 xv = *reinterpret_cast<const float4*>(&tile[c * 64 + p4]);
    float4 wv = *reinterpret_cast<const float4*>(&wlT[c * 64 + o4]);
    float xs[4] = {xv.x, xv.y, xv.z, xv.w};
#pragma unroll
    for (int p = 0; p < 4; ++p) {
      acc[p][0] = fmaf(wv.x, xs[p], acc[p][0]);
      acc[p][1] = fmaf(wv.y, xs[p], acc[p][1]);
      acc[p][2] = fmaf(wv.z, xs[p], acc[p][2]);
      acc[p][3] = fmaf(wv.w, xs[p], acc[p][3]);
    }
  }
  if (which != 2) {
#pragma unroll
    for (int p = 0; p < 4; ++p) {
      size_t idx = ((size_t)b * N_ + pb + p4 + p) * 64 + o4;
      u16x4 hv, lv;
#pragma unroll
      for (int o = 0; o < 4; ++o) {
        unsigned short hi = b16(acc[p][o]);
        hv[o] = hi;
        lv[o] = b16(acc[p][o] - fromb16(hi));
      }
      *reinterpret_cast<u16x4*>(&us[hU + idx]) = hv;
      *reinterpret_cast<u16x4*>(&us[lU + idx]) = lv;
    }
  } else {
#pragma unroll
    for (int o = 0; o < 4; ++o) {
      u16x4 hv;
#pragma unroll
      for (int p = 0; p < 4; ++p) hv[p] = b16(acc[p][o]);
      size_t idx = ((size_t)(b * 64 + o4 + o)) * N_ + pb + p4;
      *reinterpret_cast<u16x4*>(&us[VXH_U + idx]) = hv;   // V^T directly, no LDS transpose
    }
  }
}

// ---------------- K3: MFMA flash attention (R4 exact: Vth LDS dbuf, scalar P, per-lane softmax) ----------------
__global__ __launch_bounds__(256) void k_attn(float* __restrict__ ws) {
  unsigned short* us = (unsigned short*)ws;
  int blk = blockIdx.x;
  int half = blk & 1; blk >>= 1;
  int qt = blk & 63;  blk >>= 6;
  int b  = blk & 1;   blk >>= 1;
  int at = blk;
  const unsigned short* QH = us + (at ? QGH_U : QXH_U);
  const unsigned short* QL = us + (at ? QGL_U : QXL_U);
  const unsigned short* KHg = us + (at ? KGH_U : KXH_U);
  const unsigned short* KLg = us + (at ? KGL_U : KXL_U);
  const unsigned short* VHg = us + VXH_U;
  float* Pg = ws + (at ? (half ? P1G_OFF : GG_OFF) : (half ? P1X_OFF : XG_OFF))
            + (size_t)b * CN + qt * 64;

  __shared__ unsigned short Kh[2][4096], Kl[2][4096], Vth[2][4096], Ph[4096];

  int t = threadIdx.x;
  int w = t >> 6, lane = t & 63, quad = lane >> 4, l15 = lane & 15;
  int swz = l15 & 7;

  short8 qh[2], ql[2];
  {
    size_t qbase = ((size_t)b * N_ + qt * 64 + 16 * w + l15) * 64;
#pragma unroll
    for (int ks = 0; ks < 2; ++ks) {
      qh[ks] = *reinterpret_cast<const short8*>(&QH[qbase + ks * 32 + quad * 8]);
      ql[ks] = *reinterpret_cast<const short8*>(&QL[qbase + ks * 32 + quad * 8]);
    }
  }

  short8 ones;
#pragma unroll
  for (int j = 0; j < 8; ++j) ones[j] = (short)0x3F80;  // bf16 1.0

  int mt0 = half * 32, mt1 = half * 32 + 32;

  u16x8 rkh[2], rkl[2], rvh[2];
  size_t ko = ((size_t)b * N_ + (size_t)mt0 * 64 + (t >> 3)) * 64 + (size_t)(t & 7) * 8;
  size_t vo = ((size_t)(b * 64) + (t >> 3)) * N_ + (size_t)mt0 * 64 + (size_t)(t & 7) * 8;
  auto prefetch = [&]() {
    rkh[0] = *reinterpret_cast<const u16x8*>(&KHg[ko]);
    rkl[0] = *reinterpret_cast<const u16x8*>(&KLg[ko]);
    rkh[1] = *reinterpret_cast<const u16x8*>(&KHg[ko + 2048]);
    rkl[1] = *reinterpret_cast<const u16x8*>(&KLg[ko + 2048]);
    rvh[0] = *reinterpret_cast<const u16x8*>(&VHg[vo]);
    rvh[1] = *reinterpret_cast<const u16x8*>(&VHg[vo + (size_t)32 * N_]);
    ko += 4096; vo += 64;
  };
  int wr0 = t >> 3, wch = t & 7;
  int woff = wr0 * 64 + ((wch ^ (wr0 & 7)) << 3);
  auto writebuf = [&](int par) {
    *reinterpret_cast<u16x8*>(&Kh[par][woff]) = rkh[0];
    *reinterpret_cast<u16x8*>(&Kl[par][woff]) = rkl[0];
    *reinterpret_cast<u16x8*>(&Vth[par][woff]) = rvh[0];
    *reinterpret_cast<u16x8*>(&Kh[par][woff + 2048]) = rkh[1];
    *reinterpret_cast<u16x8*>(&Kl[par][woff + 2048]) = rkl[1];
    *reinterpret_cast<u16x8*>(&Vth[par][woff + 2048]) = rvh[1];
  };

  f32x4 Oa[4] = {{0.f, 0.f, 0.f, 0.f}, {0.f, 0.f, 0.f, 0.f},
                 {0.f, 0.f, 0.f, 0.f}, {0.f, 0.f, 0.f, 0.f}};
  f32x4 La = {0.f, 0.f, 0.f, 0.f};   // L in element 0 (ones-row MFMA; rows identical)
  float M = -1e30f;                  // per-lane: pixel n = 16w + l15

  int phb = (16 * w + l15) * 64;
  int mh = quad >> 1, mlw = (quad & 1) * 4;

  prefetch();
  writebuf(0);
  __syncthreads();
  for (int mt = mt0; mt < mt1; ++mt) {
    int pb = (mt - mt0) & 1;
    if (mt + 1 < mt1) prefetch();  // global latency overlaps tile compute

    // S^T[m][n]: m = ms*16 + quad*4 + reg, n = 16w + l15 (swapped operands)
    f32x4 S[4];
    __builtin_amdgcn_s_setprio(1);
#pragma unroll
    for (int ms = 0; ms < 4; ++ms) {
      f32x4 a0 = {0.f, 0.f, 0.f, 0.f}, a1 = {0.f, 0.f, 0.f, 0.f};
      int row = ms * 16 + l15;
#pragma unroll
      for (int ks = 0; ks < 2; ++ks) {
        int off = row * 64 + (((ks * 4 + quad) ^ swz) << 3);
        short8 khf = *reinterpret_cast<const short8*>(&Kh[pb][off]);
        short8 klf = *reinterpret_cast<const short8*>(&Kl[pb][off]);
        f32x4& a = ks ? a1 : a0;
        a = MFMA_BF16(khf, ql[ks], a, 0, 0, 0);
        a = MFMA_BF16(klf, qh[ks], a, 0, 0, 0);
        a = MFMA_BF16(khf, qh[ks], a, 0, 0, 0);
      }
      S[ms] = a0 + a1;
    }
    __builtin_amdgcn_s_setprio(0);

    // in-lane max over 16 values + 2-step cross-quad butterfly
    float m0 = fmaxf(fmaxf(S[0][0], S[0][1]), fmaxf(S[0][2], S[0][3]));
    float m1 = fmaxf(fmaxf(S[1][0], S[1][1]), fmaxf(S[1][2], S[1][3]));
    float m2 = fmaxf(fmaxf(S[2][0], S[2][1]), fmaxf(S[2][2], S[2][3]));
    float m3 = fmaxf(fmaxf(S[3][0], S[3][1]), fmaxf(S[3][2], S[3][3]));
    float tm = fmaxf(fmaxf(m0, m1), fmaxf(m2, m3));
    tm = fmaxf(tm, __shfl_xor(tm, 16, 64));
    tm = fmaxf(tm, __shfl_xor(tm, 32, 64));
    float mn = fmaxf(M, tm);
    float al = __expf(M - mn);
    M = mn;
#pragma unroll
    for (int ms = 0; ms < 4; ++ms) {
      int goff = phb + ((((ms << 1) + mh) ^ swz) << 3) + mlw;
#pragma unroll
      for (int r = 0; r < 4; ++r) {
        float p = __expf(S[ms][r] - mn);
        Ph[goff + r] = b16(p);   // wave-private rows -> no barrier needed
      }
    }
#pragma unroll
    for (int cs = 0; cs < 4; ++cs) {
      Oa[cs][0] *= al; Oa[cs][1] *= al; Oa[cs][2] *= al; Oa[cs][3] *= al;
    }
    La[0] *= al;

    // O^T += V^T P^T, V hi-only: 10 MFMAs (incl. 2 ones-row for L), 10 ds_reads/tile
    __builtin_amdgcn_s_setprio(1);
#pragma unroll
    for (int ks = 0; ks < 2; ++ks) {
      int poff = phb + (((ks * 4 + quad) ^ swz) << 3);
      short8 phf = *reinterpret_cast<const short8*>(&Ph[poff]);
      La = MFMA_BF16(ones, phf, La, 0, 0, 0);   // row-sums of P == L partials
#pragma unroll
      for (int cs = 0; cs < 4; ++cs) {
        int voff = (cs * 16 + l15) * 64 + (((ks * 4 + quad) ^ swz) << 3);
        short8 vhf = *reinterpret_cast<const short8*>(&Vth[pb][voff]);
        Oa[cs] = MFMA_BF16(vhf, phf, Oa[cs], 0, 0, 0);
      }
    }
    __builtin_amdgcn_s_setprio(0);

    if (mt + 1 < mt1) writebuf(pb ^ 1);  // fenced by previous iteration's barrier
    __syncthreads();
  }

#pragma unroll
  for (int cs = 0; cs < 4; ++cs) {
#pragma unroll
    for (int r = 0; r < 4; ++r) {
      int c = cs * 16 + quad * 4 + r;
      Pg[(size_t)c * N_ + 16 * w + l15] = Oa[cs][r];
    }
  }
  if (quad == 0) {
    int mlb = ((at * 2 + half) * 2 + b) * 4096 + qt * 64 + 16 * w + l15;
    ws[ML_OFF + mlb] = M;
    ws[MLL_OFF + mlb] = La[0];   // La col = pixel 16w+l15, rows identical
  }
}

// ---------------- K4: merge halves + combine ----------------
__global__ __launch_bounds__(256) void k_merge(float* __restrict__ ws,
                                               const float* __restrict__ gm_p,
                                               const float* __restrict__ al_p) {
  size_t i4 = (size_t)blockIdx.x * 256 + threadIdx.x;
  size_t i = i4 * 4;
  int n = (int)(i & 4095);
  int b = (int)(i >> 18);
  float gm = gm_p[0], al = al_p[0];
  float4 p0x = *reinterpret_cast<const float4*>(ws + XG_OFF + i);
  float4 p1x = *reinterpret_cast<const float4*>(ws + P1X_OFF + i);
  float4 p0g = *reinterpret_cast<const float4*>(ws + GG_OFF + i);
  float4 p1g = *reinterpret_cast<const float4*>(ws + P1G_OFF + i);
  float4 M0x = *reinterpret_cast<const float4*>(ws + ML_OFF  + (0 + b) * 4096 + n);
  float4 L0x = *reinterpret_cast<const float4*>(ws + MLL_OFF + (0 + b) * 4096 + n);
  float4 M1x = *reinterpret_cast<const float4*>(ws + ML_OFF  + (2 + b) * 4096 + n);
  float4 L1x = *reinterpret_cast<const float4*>(ws + MLL_OFF + (2 + b) * 4096 + n);
  float4 M0g = *reinterpret_cast<const float4*>(ws + ML_OFF  + (4 + b) * 4096 + n);
  float4 L0g = *reinterpret_cast<const float4*>(ws + MLL_OFF + (4 + b) * 4096 + n);
  float4 M1g = *reinterpret_cast<const float4*>(ws + ML_OFF  + (6 + b) * 4096 + n);
  float4 L1g = *reinterpret_cast<const float4*>(ws + MLL_OFF + (6 + b) * 4096 + n);
  const float* p0xv = (const float*)&p0x; const float* p1xv = (const float*)&p1x;
  const float* p0gv = (const float*)&p0g; const float* p1gv = (const float*)&p1g;
  const float* m0xv = (const float*)&M0x; const float* l0xv = (const float*)&L0x;
  const float* m1xv = (const float*)&M1x; const float* l1xv = (const float*)&L1x;
  const float* m0gv = (const float*)&M0g; const float* l0gv = (const float*)&L0g;
  const float* m1gv = (const float*)&M1g; const float* l1gv = (const float*)&L1g;
  float4 go, ob;
  float* gov = (float*)&go; float* obv = (float*)&ob;
#pragma unroll
  for (int l = 0; l < 4; ++l) {
    float mx = fmaxf(m0xv[l], m1xv[l]);
    float w0 = __expf(m0xv[l] - mx), w1 = __expf(m1xv[l] - mx);
    float xc = (p0xv[l] * w0 + p1xv[l] * w1) / (l0xv[l] * w0 + l1xv[l] * w1);
    float mg = fmaxf(m0gv[l], m1gv[l]);
    float v0 = __expf(m0gv[l] - mg), v1 = __expf(m1gv[l] - mg);
    float gc = (p0gv[l] * v0 + p1gv[l] * v1) / (l0gv[l] * v0 + l1gv[l] * v1);
    gov[l] = gc;
    obv[l] = gm * xc + al * gc;
  }
  *reinterpret_cast<float4*>(ws + GG_OFF + i) = go;  // GO
  *reinterpret_cast<float4*>(ws + QX_OFF + i) = ob;  // OB
}

// ---------------- K5: u = leaky(conv3x3(leaky(out), c1)), channel-split, 2 rows/wave ----------------
__global__ __launch_bounds__(256) void k_conv1(float* __restrict__ ws,
                                               const float* __restrict__ c1w,
                                               const float* __restrict__ c1b) {
  int blk = blockIdx.x;  // 1024 = b*512 + og*32 + rt
  int rt = blk & 31; blk >>= 5;
  int og  = blk & 15; blk >>= 4;
  int b   = blk;
  int o0 = og * 4;
  int row0 = rt * 2;
  __shared__ __align__(16) float4 wl4[576];
  __shared__ float part[4][4][128];
  int t = threadIdx.x;
  int wv = t >> 6, px = t & 63;
  {
    float* wlf = (float*)wl4;
    for (int idx = t; idx < 2304; idx += 256)
      wlf[idx] = c1w[(size_t)(o0 + (idx & 3)) * 576 + (idx >> 2)];
  }
  float mask[4]; int rcl[4];
#pragma unroll
  for (int k = 0; k < 4; ++k) {
    int ri = row0 - 1 + k;
    mask[k] = (ri >= 0 && ri < 64) ? 1.f : 0.f;
    rcl[k] = ri < 0 ? 0 : (ri > 63 ? 63 : ri);
  }
  int c0 = wv * 16;
  const float* base = ws + OB_OFF + (size_t)b * CN + (size_t)c0 * N_ + px;
  float r[4][16];
#pragma unroll
  for (int i = 0; i < 16; ++i)
#pragma unroll
    for (int k = 0; k < 4; ++k)
      r[k][i] = leaky(base[(size_t)i * N_ + (size_t)rcl[k] * 64]) * mask[k];
  float acc[2][4] = {};
  auto tap = [&](int ch, float v0, float v1, float v2, float v3) {
    float v[4] = {v0, v1, v2, v3};
    float lf[4], rg[4];
#pragma unroll
    for (int k = 0; k < 4; ++k) {
      lf[k] = __shfl_up(v[k], 1, 64);   if (px == 0)  lf[k] = 0.f;
      rg[k] = __shfl_down(v[k], 1, 64); if (px == 63) rg[k] = 0.f;
    }
#pragma unroll
    for (int ky = 0; ky < 3; ++ky) {
      float4 w0 = wl4[ch * 9 + ky * 3 + 0];
      float4 w1 = wl4[ch * 9 + ky * 3 + 1];
      float4 w2 = wl4[ch * 9 + ky * 3 + 2];
#pragma unroll
      for (int j = 0; j < 2; ++j) {
        int k = j + ky;
        acc[j][0] = fmaf(w0.x, lf[k], fmaf(w1.x, v[k], fmaf(w2.x, rg[k], acc[j][0])));
        acc[j][1] = fmaf(w0.y, lf[k], fmaf(w1.y, v[k], fmaf(w2.y, rg[k], acc[j][1])));
        acc[j][2] = fmaf(w0.z, lf[k], fmaf(w1.z, v[k], fmaf(w2.z, rg[k], acc[j][2])));
        acc[j][3] = fmaf(w0.w, lf[k], fmaf(w1.w, v[k], fmaf(w2.w, rg[k], acc[j][3])));
      }
    }
  };
  __syncthreads();
#pragma unroll
  for (int i = 0; i < 16; ++i) tap(c0 + i, r[0][i], r[1][i], r[2][i], r[3][i]);
#pragma unroll
  for (int j = 0; j < 2; ++j)
#pragma unroll
    for (int oo = 0; oo < 4; ++oo) part[wv][oo][j * 64 + px] = acc[j][oo];
  __syncthreads();
  int oc = t >> 6;
  float bb = c1b[o0 + oc];
  float* ub = ws + UB_OFF + (size_t)b * CN;
#pragma unroll
  for (int j = 0; j < 2; ++j) {
    int jp = j * 64 + px;
    float s = (part[0][oc][jp] + part[1][oc][jp]) + (part[2][oc][jp] + part[3][oc][jp]);
    ub[(size_t)(o0 + oc) * N_ + (size_t)(row0 + j) * 64 + px] = leaky(s + bb);
  }
}

// ---------------- K6: final, channel-split + fused sc dot, 2 rows/wave ----------------
__global__ __launch_bounds__(256) void k_final(const float* __restrict__ ws,
                                               const float* __restrict__ c2w,
                                               const float* __restrict__ c2b,
                                               const float* __restrict__ scw,
                                               const float* __restrict__ scb,
                                               float* __restrict__ out) {
  int blk = blockIdx.x;  // 1024 = b*512 + og*32 + rt
  int rt = blk & 31; blk >>= 5;
  int og  = blk & 15; blk >>= 4;
  int b   = blk;
  int o0 = og * 4;
  int row0 = rt * 2;
  __shared__ __align__(16) float4 wl4[576];
  __shared__ __align__(16) float4 scl4[64];
  __shared__ float part[4][4][128];
  __shared__ float part2[4][4][128];
  int t = threadIdx.x;
  int wv = t >> 6, px = t & 63;
  {
    float* wlf = (float*)wl4;
    for (int idx = t; idx < 2304; idx += 256)
      wlf[idx] = c2w[(size_t)(o0 + (idx & 3)) * 576 + (idx >> 2)];
    float* sclf = (float*)scl4;
    if (t < 256) {
      int idx = t;
      sclf[idx] = scw[(size_t)(o0 + (idx & 3)) * 64 + (idx >> 2)];
    }
  }
  float mask[4]; int rcl[4];
#pragma unroll
  for (int k = 0; k < 4; ++k) {
    int ri = row0 - 1 + k;
    mask[k] = (ri >= 0 && ri < 64) ? 1.f : 0.f;
    rcl[k] = ri < 0 ? 0 : (ri > 63 ? 63 : ri);
  }
  int c0 = wv * 16;
  const float* base = ws + UB_OFF + (size_t)b * CN + (size_t)c0 * N_ + px;
  const float* obb  = ws + OB_OFF + (size_t)b * CN + (size_t)c0 * N_ + px;
  float r[4][16], ob[2][16];
#pragma unroll
  for (int i = 0; i < 16; ++i) {
#pragma unroll
    for (int k = 0; k < 4; ++k)
      r[k][i] = base[(size_t)i * N_ + (size_t)rcl[k] * 64] * mask[k];
#pragma unroll
    for (int j = 0; j < 2; ++j)
      ob[j][i] = obb[(size_t)i * N_ + (size_t)(row0 + j) * 64];
  }
  float acc[2][4] = {};
  float scp[2][4] = {};
  auto tap = [&](int ch, float v0, float v1, float v2, float v3) {
    float v[4] = {v0, v1, v2, v3};
    float lf[4], rg[4];
#pragma unroll
    for (int k = 0; k < 4; ++k) {
      lf[k] = __shfl_up(v[k], 1, 64);   if (px == 0)  lf[k] = 0.f;
      rg[k] = __shfl_down(v[k], 1, 64); if (px == 63) rg[k] = 0.f;
    }
#pragma unroll
    for (int ky = 0; ky < 3; ++ky) {
      float4 w0 = wl4[ch * 9 + ky * 3 + 0];
      float4 w1 = wl4[ch * 9 + ky * 3 + 1];
      float4 w2 = wl4[ch * 9 + ky * 3 + 2];
#pragma unroll
      for (int j = 0; j < 2; ++j) {
        int k = j + ky;
        acc[j][0] = fmaf(w0.x, lf[k], fmaf(w1.x, v[k], fmaf(w2.x, rg[k], acc[j][0])));
        acc[j][1] = fmaf(w0.y, lf[k], fmaf(w1.y, v[k], fmaf(w2.y, rg[k], acc[j][1])));
        acc[j][2] = fmaf(w0.z, lf[k], fmaf(w1.z, v[k], fmaf(w2.z, rg[k], acc[j][2])));
        acc[j][3] = fmaf(w0.w, lf[k], fmaf(w1.w, v[k], fmaf(w2.w, rg[k], acc[j][3])));
      }
    }
  };
  __syncthreads();
#pragma unroll
  for (int i = 0; i < 16; ++i) {
    tap(c0 + i, r[0][i], r[1][i], r[2][i], r[3][i]);
    float4 s4 = scl4[c0 + i];
#pragma unroll
    for (int j = 0; j < 2; ++j) {
      scp[j][0] = fmaf(s4.x, ob[j][i], scp[j][0]);
      scp[j][1] = fmaf(s4.y, ob[j][i], scp[j][1]);
      scp[j][2] = fmaf(s4.z, ob[j][i], scp[j][2]);
      scp[j][3] = fmaf(s4.w, ob[j][i], scp[j][3]);
    }
  }
#pragma unroll
  for (int j = 0; j < 2; ++j)
#pragma unroll
    for (int oo = 0; oo < 4; ++oo) {
      part[wv][oo][j * 64 + px] = acc[j][oo];
      part2[wv][oo][j * 64 + px] = scp[j][oo];
    }
  __syncthreads();
  int oc = t >> 6;
  float c2bv = c2b[o0 + oc];
  float scbv = scb[o0 + oc];
  const float* go = ws + GO_OFF + (size_t)b * CN;
  float* ob_out = out + (size_t)b * CN;
#pragma unroll
  for (int j = 0; j < 2; ++j) {
    int jp = j * 64 + px;
    float s  = (part[0][oc][jp] + part[1][oc][jp]) + (part[2][oc][jp] + part[3][oc][jp]);
    float sc = (part2[0][oc][jp] + part2[1][oc][jp]) + (part2[2][oc][jp] + part2[3][oc][jp]);
    size_t pix = (size_t)(row0 + j) * 64 + px;
    float gvv = go[(size_t)(o0 + oc) * N_ + pix];
    ob_out[(size_t)(o0 + oc) * N_ + pix] = (s + c2bv) + (sc + scbv) * gvv;
  }
}

extern "C" void kernel_launch(void* const* d_in, const int* in_sizes, int n_in,
                              void* d_out, int out_size, void* d_ws, size_t ws_size,
                              hipStream_t stream) {
  const float* x     = (const float*)d_in[0];
  const float* guide = (const float*)d_in[1];
  const float* lin_w = (const float*)d_in[2];
  const float* lin_b = (const float*)d_in[3];
  const float* cw    = (const float*)d_in[4];
  const float* xq_w  = (const float*)d_in[5];
  const float* xq_b  = (const float*)d_in[6];
  const float* xk_w  = (const float*)d_in[7];
  const float* xk_b  = (const float*)d_in[8];
  const float* xv_w  = (const float*)d_in[9];
  const float* xv_b  = (const float*)d_in[10];
  const float* gq_w  = (const float*)d_in[11];
  const float* gq_b  = (const float*)d_in[12];
  const float* gk_w  = (const float*)d_in[13];
  const float* gk_b  = (const float*)d_in[14];
  const float* gamma = (const float*)d_in[15];
  const float* alpha = (const float*)d_in[16];
  const float* c1_w  = (const float*)d_in[17];
  const float* c1_b  = (const float*)d_in[18];
  const float* c2_w  = (const float*)d_in[19];
  const float* c2_b  = (const float*)d_in[20];
  const float* sc_w  = (const float*)d_in[21];
  const float* sc_b  = (const float*)d_in[22];
  float* out = (float*)d_out;
  float* ws = (float*)d_ws;

  k_ca<<<256, 64, 0, stream>>>(x, guide, lin_w, lin_b,
                               xq_w, xk_w, xv_w, gq_w, gk_w, ws);
  k_coordconv<<<2048, 256, 0, stream>>>(x, guide, cw, ws);
  k_proj<<<640, 256, 0, stream>>>(ws, xq_b, xk_b, xv_b, gq_b, gk_b);
  k_attn<<<512, 256, 0, stream>>>(ws);
  k_merge<<<512, 256, 0, stream>>>(ws, gamma, alpha);
  k_conv1<<<1024, 256, 0, stream>>>(ws, c1_w, c1_b);
  k_final<<<1024, 256, 0, stream>>>(ws, c2_w, c2_b, sc_w, sc_b, out);
}

// Round 11
// 234.987 us; speedup vs baseline: 1.4130x; 1.0269x over previous
//
#include <hip/hip_runtime.h>
#include <hip/hip_bf16.h>

using bf16 = __hip_bfloat16;

#define DI __device__ __forceinline__

typedef __attribute__((ext_vector_type(8))) short short8;
typedef __attribute__((ext_vector_type(8))) unsigned short u16x8;
typedef __attribute__((ext_vector_type(4))) unsigned short u16x4;
typedef __attribute__((ext_vector_type(4))) float f32x4;

#define MFMA_BF16 __builtin_amdgcn_mfma_f32_16x16x32_bf16

DI float leaky(float x) { return x > 0.f ? x : 0.1f * x; }

// bf16 split helpers (RNE). x = hi + lo to ~2^-16 relative.
DI unsigned short b16(float x) {
  union { float f; unsigned u; } v; v.f = x;
  unsigned r = v.u + 0x7FFFu + ((v.u >> 16) & 1u);
  return (unsigned short)(r >> 16);
}
DI float fromb16(unsigned short h) {
  union { unsigned u; float f; } v; v.u = ((unsigned)h) << 16; return v.f;
}

// Problem constants: B=2, C=64, H=64, W=64, N=4096. Inputs fp32 (R3/R4).
// NOTE R13: hipLaunchCooperativeKernel fails silently under graph capture here.
// Precision ladder (validated): Q/K split bf16, P hi-only, V hi-only in PV,
// L via ones-row MFMA. R2: swapped QK^T -> lane owns one pixel.
// ATTN LESSONS (R5-R7): 8-wave K-split loses; launch_bounds reg-pinning
// spills; V-direct-from-global loses. R4 attn frozen (66us in this mix).
// R8 LESSON: compiler does NOT scalarize uniform global reads -> weights in
// LDS. R9: convs 2 rows/wave -> 241.8. R10: proj 4ox4px re-tile ~neutral
// (proj was already small).
// R11: coordconv+conv1 4 rows/wave (weight ds_read/row amortizes 4x, halo
// 6 shfl-rows for 4 outputs; ~20% less issue/row). k_final stays 2-row
// (ob[4][16] would push ~190 VGPR -> spill). CA folded into proj staging
// (XG/GG only feed proj; same single multiply -> bit-identical; kills
// k_ca->coordconv serialization).
static constexpr int N_ = 4096;
static constexpr size_t CN = 262144;
static constexpr size_t BCN = 524288;

// ---- Workspace layout (float indices) ----
static constexpr size_t XG_OFF = 137104;
static constexpr size_t GG_OFF = XG_OFF + BCN;
static constexpr size_t QX_OFF = GG_OFF + BCN;
static constexpr size_t KX_OFF = QX_OFF + BCN;
static constexpr size_t VX_OFF = KX_OFF + BCN;
static constexpr size_t QG_OFF = VX_OFF + BCN;
static constexpr size_t KG_OFF = QG_OFF + BCN;
static constexpr size_t P1X_OFF = KG_OFF + BCN;
static constexpr size_t P1G_OFF = P1X_OFF + BCN;
static constexpr size_t ML_OFF  = P1G_OFF + BCN;
static constexpr size_t MLL_OFF = ML_OFF + 32768;
static constexpr size_t CA_OFF = ML_OFF;        // 256 floats; consumed by proj before attn writes ML
static constexpr size_t WT_OFF = ML_OFF + 256;  // 5*4096 transposed proj weights; consumed by proj before attn
static constexpr size_t OB_OFF = QX_OFF;
static constexpr size_t UB_OFF = KX_OFF;
static constexpr size_t GO_OFF = GG_OFF;
static constexpr size_t QXH_U = QX_OFF * 2, QXL_U = QXH_U + BCN;
static constexpr size_t KXH_U = KX_OFF * 2, KXL_U = KXH_U + BCN;
static constexpr size_t VXH_U = VX_OFF * 2;
static constexpr size_t QGH_U = QG_OFF * 2, QGL_U = QGH_U + BCN;
static constexpr size_t KGH_U = KG_OFF * 2, KGL_U = KGH_U + BCN;
// Peak 19.7 MB (validated R6-R14)

// ---------------- K0: channel-attention scales + proj weight transpose ----------------
__global__ __launch_bounds__(64) void k_ca(const float* __restrict__ x,
                                           const float* __restrict__ g,
                                           const float* __restrict__ lw_p,
                                           const float* __restrict__ lb_p,
                                           const float* __restrict__ xqw,
                                           const float* __restrict__ xkw,
                                           const float* __restrict__ xvw,
                                           const float* __restrict__ gqw,
                                           const float* __restrict__ gkw,
                                           float* __restrict__ ws) {
  int blk = blockIdx.x;
  int ch = blk & 63; blk >>= 6;
  int b  = blk & 1;  blk >>= 1;
  int src = blk;
  const float* in = (src ? g : x) + ((size_t)(b * 64 + ch)) * N_;
  int t = threadIdx.x;
  float s = 0.f;
#pragma unroll
  for (int i = 0; i < 16; ++i) {
    float4 v = *reinterpret_cast<const float4*>(in + i * 256 + t * 4);
    s += (v.x + v.y) + (v.z + v.w);
  }
#pragma unroll
  for (int d = 1; d < 64; d <<= 1) s += __shfl_xor(s, d, 64);
  if (t == 0) {
    float p = s * (1.f / 4096.f);
    float lwv = lw_p[0], lbv = lb_p[0];
    float h = leaky(lwv * p + lbv);
    ws[CA_OFF + (src * 2 + b) * 64 + ch] = 1.f / (1.f + expf(-(lwv * h + lbv)));
  }
  // transpose 5 proj weight mats (O x C -> C x O) into WT region (coalesced reads)
  int gid = blockIdx.x * 64 + t;
  for (int idx = gid; idx < 20480; idx += 16384) {
    int m = idx >> 12, e = idx & 4095;
    const float* wp = (m == 0) ? xqw : (m == 1) ? xkw : (m == 2) ? xvw : (m == 3) ? gqw : gkw;
    ws[WT_OFF + (m << 12) + ((e & 63) << 6) + (e >> 6)] = wp[e];
  }
}

// ---------------- K1: coord-conv 3x3, channel-split, 4 rows/wave ----------------
__global__ __launch_bounds__(256) void k_coordconv(const float* __restrict__ x,
                                                   const float* __restrict__ g,
                                                   const float* __restrict__ cw,
                                                   float* __restrict__ ws) {
  int blk = blockIdx.x;  // 1024 = src*512 + b*256 + og*16 + rt
  int rt = blk & 15; blk >>= 4;
  int og  = blk & 15; blk >>= 4;
  int b   = blk & 1;  blk >>= 1;
  int src = blk;
  int o0 = og * 4;
  int row0 = rt * 4;
  const float* in = src ? g : x;
  float* outp = ws + (src ? GG_OFF : XG_OFF);
  __shared__ __align__(16) float4 wl4[594];   // [ch*9+tap] -> 4 oc
  __shared__ float part[4][4][256];
  int t = threadIdx.x;
  int wv = t >> 6, px = t & 63;
  {
    float* wlf = (float*)wl4;
    for (int idx = t; idx < 2376; idx += 256)
      wlf[idx] = cw[(size_t)(o0 + (idx & 3)) * 594 + (idx >> 2)];
  }
  // input rows row0-1 .. row0+4 (k = 0..5)
  float mask[6]; int rcl[6];
#pragma unroll
  for (int k = 0; k < 6; ++k) {
    int ri = row0 - 1 + k;
    mask[k] = (ri >= 0 && ri < 64) ? 1.f : 0.f;
    rcl[k] = ri < 0 ? 0 : (ri > 63 ? 63 : ri);
  }
  int c0 = wv * 16;
  const float* base = in + ((size_t)(b * 64 + c0)) * N_ + px;
  float r[16][6];
#pragma unroll
  for (int i = 0; i < 16; ++i)
#pragma unroll
    for (int k = 0; k < 6; ++k)
      r[i][k] = base[(size_t)i * N_ + (size_t)rcl[k] * 64] * mask[k];
  float acc[4][4] = {};
  auto tap = [&](int ch, const float* v) {
    float lf[6], rg[6];
#pragma unroll
    for (int k = 0; k < 6; ++k) {
      lf[k] = __shfl_up(v[k], 1, 64);   if (px == 0)  lf[k] = 0.f;
      rg[k] = __shfl_down(v[k], 1, 64); if (px == 63) rg[k] = 0.f;
    }
#pragma unroll
    for (int ky = 0; ky < 3; ++ky) {
      float4 w0 = wl4[ch * 9 + ky * 3 + 0];
      float4 w1 = wl4[ch * 9 + ky * 3 + 1];
      float4 w2 = wl4[ch * 9 + ky * 3 + 2];
#pragma unroll
      for (int j = 0; j < 4; ++j) {
        int k = j + ky;
        acc[j][0] = fmaf(w0.x, lf[k], fmaf(w1.x, v[k], fmaf(w2.x, rg[k], acc[j][0])));
        acc[j][1] = fmaf(w0.y, lf[k], fmaf(w1.y, v[k], fmaf(w2.y, rg[k], acc[j][1])));
        acc[j][2] = fmaf(w0.z, lf[k], fmaf(w1.z, v[k], fmaf(w2.z, rg[k], acc[j][2])));
        acc[j][3] = fmaf(w0.w, lf[k], fmaf(w1.w, v[k], fmaf(w2.w, rg[k], acc[j][3])));
      }
    }
  };
  __syncthreads();   // weights ready
#pragma unroll
  for (int i = 0; i < 16; ++i) tap(c0 + i, r[i]);
  if (wv == 3) {
    // ch 64: xx varies along px (zero-padded rows/cols like real channels)
    float xx = (float)px * (2.f / 63.f) - 1.f;
    float vx[6];
#pragma unroll
    for (int k = 0; k < 6; ++k) vx[k] = mask[k] * xx;
    tap(64, vx);
    // ch 65: yy constant along px, varies by row
    float vy[6];
#pragma unroll
    for (int k = 0; k < 6; ++k)
      vy[k] = mask[k] * ((float)(row0 - 1 + k) * (2.f / 63.f) - 1.f);
    tap(65, vy);
  }
#pragma unroll
  for (int j = 0; j < 4; ++j)
#pragma unroll
    for (int oo = 0; oo < 4; ++oo) part[wv][oo][j * 64 + px] = acc[j][oo];
  __syncthreads();
  int oc = t >> 6;
#pragma unroll
  for (int j = 0; j < 4; ++j) {
    int jp = j * 64 + px;
    float s = (part[0][oc][jp] + part[1][oc][jp]) + (part[2][oc][jp] + part[3][oc][jp]);
    outp[((size_t)(b * 64 + o0 + oc)) * N_ + (size_t)(row0 + j) * 64 + px] = s;  // CA folded into proj
  }
}

// ---------------- K2: 1x1 projections; 4o x 4px per thread, transposed weights, CA applied ----------------
__global__ __launch_bounds__(256) void k_proj(float* __restrict__ ws,
                                              const float* __restrict__ xqb,
                                              const float* __restrict__ xkb,
                                              const float* __restrict__ xvb,
                                              const float* __restrict__ gqb,
                                              const float* __restrict__ gkb) {
  int blk = blockIdx.x;  // 5 * 2 * 64
  int pt = blk & 63; blk >>= 6;
  int b  = blk & 1;  blk >>= 1;
  int which = blk;
  size_t in_o = (which <= 2) ? XG_OFF : GG_OFF;
  int s2b = ((which <= 2) ? 0 : 2) + b;
  const float* bp = (which == 0) ? xqb : (which == 1) ? xkb : (which == 2) ? xvb
                   : (which == 3) ? gqb : gkb;
  size_t hU = 0, lU = 0;
  if (which == 0)      { hU = QXH_U; lU = QXL_U; }
  else if (which == 1) { hU = KXH_U; lU = KXL_U; }
  else if (which == 3) { hU = QGH_U; lU = QGL_U; }
  else if (which == 4) { hU = KGH_U; lU = KGL_U; }

  __shared__ __align__(16) float tile[4096];   // [c][px], CA-scaled
  __shared__ __align__(16) float wlT[4096];    // [c][o]
  __shared__ __align__(16) float bl[64];
  unsigned short* us = (unsigned short*)ws;
  int t = threadIdx.x;
  int pb = pt * 64;
  const float* in0 = ws + in_o + (size_t)b * CN + pb;
  const float* caP = ws + CA_OFF + s2b * 64;
  for (int c0 = (t >> 6); c0 < 64; c0 += 4)
    tile[c0 * 64 + (t & 63)] = in0[(size_t)c0 * N_ + (t & 63)] * caP[c0];
  const float* wtG = ws + WT_OFF + (size_t)which * 4096;
  for (int idx = t; idx < 4096; idx += 256)
    wlT[idx] = wtG[idx];
  if (t < 64) bl[t] = bp[t];
  __syncthreads();
  int o4 = (t & 15) * 4, p4 = (t >> 4) * 4;
  float4 bv4 = *reinterpret_cast<const float4*>(&bl[o4]);
  float acc[4][4];   // [p'][o']
#pragma unroll
  for (int p = 0; p < 4; ++p) {
    acc[p][0] = bv4.x; acc[p][1] = bv4.y; acc[p][2] = bv4.z; acc[p][3] = bv4.w;
  }
#pragma unroll 8
  for (int c = 0; c < 64; ++c) {
    float4 xv = *reinterpret_cast<const float4*>(&tile[c * 64 + p4]);
    float4 wv = *reinterpret_cast<const float4*>(&wlT[c * 64 + o4]);
    float xs[4] = {xv.x, xv.y, xv.z, xv.w};
#pragma unroll
    for (int p = 0; p < 4; ++p) {
      acc[p][0] = fmaf(wv.x, xs[p], acc[p][0]);
      acc[p][1] = fmaf(wv.y, xs[p], acc[p][1]);
      acc[p][2] = fmaf(wv.z, xs[p], acc[p][2]);
      acc[p][3] = fmaf(wv.w, xs[p], acc[p][3]);
    }
  }
  if (which != 2) {
#pragma unroll
    for (int p = 0; p < 4; ++p) {
      size_t idx = ((size_t)b * N_ + pb + p4 + p) * 64 + o4;
      u16x4 hv, lv;
#pragma unroll
      for (int o = 0; o < 4; ++o) {
        unsigned short hi = b16(acc[p][o]);
        hv[o] = hi;
        lv[o] = b16(acc[p][o] - fromb16(hi));
      }
      *reinterpret_cast<u16x4*>(&us[hU + idx]) = hv;
      *reinterpret_cast<u16x4*>(&us[lU + idx]) = lv;
    }
  } else {
#pragma unroll
    for (int o = 0; o < 4; ++o) {
      u16x4 hv;
#pragma unroll
      for (int p = 0; p < 4; ++p) hv[p] = b16(acc[p][o]);
      size_t idx = ((size_t)(b * 64 + o4 + o)) * N_ + pb + p4;
      *reinterpret_cast<u16x4*>(&us[VXH_U + idx]) = hv;   // V^T directly, no LDS transpose
    }
  }
}

// ---------------- K3: MFMA flash attention (R4 exact: Vth LDS dbuf, scalar P, per-lane softmax) ----------------
__global__ __launch_bounds__(256) void k_attn(float* __restrict__ ws) {
  unsigned short* us = (unsigned short*)ws;
  int blk = blockIdx.x;
  int half = blk & 1; blk >>= 1;
  int qt = blk & 63;  blk >>= 6;
  int b  = blk & 1;   blk >>= 1;
  int at = blk;
  const unsigned short* QH = us + (at ? QGH_U : QXH_U);
  const unsigned short* QL = us + (at ? QGL_U : QXL_U);
  const unsigned short* KHg = us + (at ? KGH_U : KXH_U);
  const unsigned short* KLg = us + (at ? KGL_U : KXL_U);
  const unsigned short* VHg = us + VXH_U;
  float* Pg = ws + (at ? (half ? P1G_OFF : GG_OFF) : (half ? P1X_OFF : XG_OFF))
            + (size_t)b * CN + qt * 64;

  __shared__ unsigned short Kh[2][4096], Kl[2][4096], Vth[2][4096], Ph[4096];

  int t = threadIdx.x;
  int w = t >> 6, lane = t & 63, quad = lane >> 4, l15 = lane & 15;
  int swz = l15 & 7;

  short8 qh[2], ql[2];
  {
    size_t qbase = ((size_t)b * N_ + qt * 64 + 16 * w + l15) * 64;
#pragma unroll
    for (int ks = 0; ks < 2; ++ks) {
      qh[ks] = *reinterpret_cast<const short8*>(&QH[qbase + ks * 32 + quad * 8]);
      ql[ks] = *reinterpret_cast<const short8*>(&QL[qbase + ks * 32 + quad * 8]);
    }
  }

  short8 ones;
#pragma unroll
  for (int j = 0; j < 8; ++j) ones[j] = (short)0x3F80;  // bf16 1.0

  int mt0 = half * 32, mt1 = half * 32 + 32;

  u16x8 rkh[2], rkl[2], rvh[2];
  size_t ko = ((size_t)b * N_ + (size_t)mt0 * 64 + (t >> 3)) * 64 + (size_t)(t & 7) * 8;
  size_t vo = ((size_t)(b * 64) + (t >> 3)) * N_ + (size_t)mt0 * 64 + (size_t)(t & 7) * 8;
  auto prefetch = [&]() {
    rkh[0] = *reinterpret_cast<const u16x8*>(&KHg[ko]);
    rkl[0] = *reinterpret_cast<const u16x8*>(&KLg[ko]);
    rkh[1] = *reinterpret_cast<const u16x8*>(&KHg[ko + 2048]);
    rkl[1] = *reinterpret_cast<const u16x8*>(&KLg[ko + 2048]);
    rvh[0] = *reinterpret_cast<const u16x8*>(&VHg[vo]);
    rvh[1] = *reinterpret_cast<const u16x8*>(&VHg[vo + (size_t)32 * N_]);
    ko += 4096; vo += 64;
  };
  int wr0 = t >> 3, wch = t & 7;
  int woff = wr0 * 64 + ((wch ^ (wr0 & 7)) << 3);
  auto writebuf = [&](int par) {
    *reinterpret_cast<u16x8*>(&Kh[par][woff]) = rkh[0];
    *reinterpret_cast<u16x8*>(&Kl[par][woff]) = rkl[0];
    *reinterpret_cast<u16x8*>(&Vth[par][woff]) = rvh[0];
    *reinterpret_cast<u16x8*>(&Kh[par][woff + 2048]) = rkh[1];
    *reinterpret_cast<u16x8*>(&Kl[par][woff + 2048]) = rkl[1];
    *reinterpret_cast<u16x8*>(&Vth[par][woff + 2048]) = rvh[1];
  };

  f32x4 Oa[4] = {{0.f, 0.f, 0.f, 0.f}, {0.f, 0.f, 0.f, 0.f},
                 {0.f, 0.f, 0.f, 0.f}, {0.f, 0.f, 0.f, 0.f}};
  f32x4 La = {0.f, 0.f, 0.f, 0.f};   // L in element 0 (ones-row MFMA; rows identical)
  float M = -1e30f;                  // per-lane: pixel n = 16w + l15

  int phb = (16 * w + l15) * 64;
  int mh = quad >> 1, mlw = (quad & 1) * 4;

  prefetch();
  writebuf(0);
  __syncthreads();
  for (int mt = mt0; mt < mt1; ++mt) {
    int pb = (mt - mt0) & 1;
    if (mt + 1 < mt1) prefetch();  // global latency overlaps tile compute

    // S^T[m][n]: m = ms*16 + quad*4 + reg, n = 16w + l15 (swapped operands)
    f32x4 S[4];
    __builtin_amdgcn_s_setprio(1);
#pragma unroll
    for (int ms = 0; ms < 4; ++ms) {
      f32x4 a0 = {0.f, 0.f, 0.f, 0.f}, a1 = {0.f, 0.f, 0.f, 0.f};
      int row = ms * 16 + l15;
#pragma unroll
      for (int ks = 0; ks < 2; ++ks) {
        int off = row * 64 + (((ks * 4 + quad) ^ swz) << 3);
        short8 khf = *reinterpret_cast<const short8*>(&Kh[pb][off]);
        short8 klf = *reinterpret_cast<const short8*>(&Kl[pb][off]);
        f32x4& a = ks ? a1 : a0;
        a = MFMA_BF16(khf, ql[ks], a, 0, 0, 0);
        a = MFMA_BF16(klf, qh[ks], a, 0, 0, 0);
        a = MFMA_BF16(khf, qh[ks], a, 0, 0, 0);
      }
      S[ms] = a0 + a1;
    }
    __builtin_amdgcn_s_setprio(0);

    // in-lane max over 16 values + 2-step cross-quad butterfly
    float m0 = fmaxf(fmaxf(S[0][0], S[0][1]), fmaxf(S[0][2], S[0][3]));
    float m1 = fmaxf(fmaxf(S[1][0], S[1][1]), fmaxf(S[1][2], S[1][3]));
    float m2 = fmaxf(fmaxf(S[2][0], S[2][1]), fmaxf(S[2][2], S[2][3]));
    float m3 = fmaxf(fmaxf(S[3][0], S[3][1]), fmaxf(S[3][2], S[3][3]));
    float tm = fmaxf(fmaxf(m0, m1), fmaxf(m2, m3));
    tm = fmaxf(tm, __shfl_xor(tm, 16, 64));
    tm = fmaxf(tm, __shfl_xor(tm, 32, 64));
    float mn = fmaxf(M, tm);
    float al = __expf(M - mn);
    M = mn;
#pragma unroll
    for (int ms = 0; ms < 4; ++ms) {
      int goff = phb + ((((ms << 1) + mh) ^ swz) << 3) + mlw;
#pragma unroll
      for (int r = 0; r < 4; ++r) {
        float p = __expf(S[ms][r] - mn);
        Ph[goff + r] = b16(p);   // wave-private rows -> no barrier needed
      }
    }
#pragma unroll
    for (int cs = 0; cs < 4; ++cs) {
      Oa[cs][0] *= al; Oa[cs][1] *= al; Oa[cs][2] *= al; Oa[cs][3] *= al;
    }
    La[0] *= al;

    // O^T += V^T P^T, V hi-only: 10 MFMAs (incl. 2 ones-row for L), 10 ds_reads/tile
    __builtin_amdgcn_s_setprio(1);
#pragma unroll
    for (int ks = 0; ks < 2; ++ks) {
      int poff = phb + (((ks * 4 + quad) ^ swz) << 3);
      short8 phf = *reinterpret_cast<const short8*>(&Ph[poff]);
      La = MFMA_BF16(ones, phf, La, 0, 0, 0);   // row-sums of P == L partials
#pragma unroll
      for (int cs = 0; cs < 4; ++cs) {
        int voff = (cs * 16 + l15) * 64 + (((ks * 4 + quad) ^ swz) << 3);
        short8 vhf = *reinterpret_cast<const short8*>(&Vth[pb][voff]);
        Oa[cs] = MFMA_BF16(vhf, phf, Oa[cs], 0, 0, 0);
      }
    }
    __builtin_amdgcn_s_setprio(0);

    if (mt + 1 < mt1) writebuf(pb ^ 1);  // fenced by previous iteration's barrier
    __syncthreads();
  }

#pragma unroll
  for (int cs = 0; cs < 4; ++cs) {
#pragma unroll
    for (int r = 0; r < 4; ++r) {
      int c = cs * 16 + quad * 4 + r;
      Pg[(size_t)c * N_ + 16 * w + l15] = Oa[cs][r];
    }
  }
  if (quad == 0) {
    int mlb = ((at * 2 + half) * 2 + b) * 4096 + qt * 64 + 16 * w + l15;
    ws[ML_OFF + mlb] = M;
    ws[MLL_OFF + mlb] = La[0];   // La col = pixel 16w+l15, rows identical
  }
}

// ---------------- K4: merge halves + combine ----------------
__global__ __launch_bounds__(256) void k_merge(float* __restrict__ ws,
                                               const float* __restrict__ gm_p,
                                               const float* __restrict__ al_p) {
  size_t i4 = (size_t)blockIdx.x * 256 + threadIdx.x;
  size_t i = i4 * 4;
  int n = (int)(i & 4095);
  int b = (int)(i >> 18);
  float gm = gm_p[0], al = al_p[0];
  float4 p0x = *reinterpret_cast<const float4*>(ws + XG_OFF + i);
  float4 p1x = *reinterpret_cast<const float4*>(ws + P1X_OFF + i);
  float4 p0g = *reinterpret_cast<const float4*>(ws + GG_OFF + i);
  float4 p1g = *reinterpret_cast<const float4*>(ws + P1G_OFF + i);
  float4 M0x = *reinterpret_cast<const float4*>(ws + ML_OFF  + (0 + b) * 4096 + n);
  float4 L0x = *reinterpret_cast<const float4*>(ws + MLL_OFF + (0 + b) * 4096 + n);
  float4 M1x = *reinterpret_cast<const float4*>(ws + ML_OFF  + (2 + b) * 4096 + n);
  float4 L1x = *reinterpret_cast<const float4*>(ws + MLL_OFF + (2 + b) * 4096 + n);
  float4 M0g = *reinterpret_cast<const float4*>(ws + ML_OFF  + (4 + b) * 4096 + n);
  float4 L0g = *reinterpret_cast<const float4*>(ws + MLL_OFF + (4 + b) * 4096 + n);
  float4 M1g = *reinterpret_cast<const float4*>(ws + ML_OFF  + (6 + b) * 4096 + n);
  float4 L1g = *reinterpret_cast<const float4*>(ws + MLL_OFF + (6 + b) * 4096 + n);
  const float* p0xv = (const float*)&p0x; const float* p1xv = (const float*)&p1x;
  const float* p0gv = (const float*)&p0g; const float* p1gv = (const float*)&p1g;
  const float* m0xv = (const float*)&M0x; const float* l0xv = (const float*)&L0x;
  const float* m1xv = (const float*)&M1x; const float* l1xv = (const float*)&L1x;
  const float* m0gv = (const float*)&M0g; const float* l0gv = (const float*)&L0g;
  const float* m1gv = (const float*)&M1g; const float* l1gv = (const float*)&L1g;
  float4 go, ob;
  float* gov = (float*)&go; float* obv = (float*)&ob;
#pragma unroll
  for (int l = 0; l < 4; ++l) {
    float mx = fmaxf(m0xv[l], m1xv[l]);
    float w0 = __expf(m0xv[l] - mx), w1 = __expf(m1xv[l] - mx);
    float xc = (p0xv[l] * w0 + p1xv[l] * w1) / (l0xv[l] * w0 + l1xv[l] * w1);
    float mg = fmaxf(m0gv[l], m1gv[l]);
    float v0 = __expf(m0gv[l] - mg), v1 = __expf(m1gv[l] - mg);
    float gc = (p0gv[l] * v0 + p1gv[l] * v1) / (l0gv[l] * v0 + l1gv[l] * v1);
    gov[l] = gc;
    obv[l] = gm * xc + al * gc;
  }
  *reinterpret_cast<float4*>(ws + GG_OFF + i) = go;  // GO
  *reinterpret_cast<float4*>(ws + QX_OFF + i) = ob;  // OB
}

// ---------------- K5: u = leaky(conv3x3(leaky(out), c1)), channel-split, 4 rows/wave ----------------
__global__ __launch_bounds__(256) void k_conv1(float* __restrict__ ws,
                                               const float* __restrict__ c1w,
                                               const float* __restrict__ c1b) {
  int blk = blockIdx.x;  // 512 = b*256 + og*16 + rt
  int rt = blk & 15; blk >>= 4;
  int og  = blk & 15; blk >>= 4;
  int b   = blk;
  int o0 = og * 4;
  int row0 = rt * 4;
  __shared__ __align__(16) float4 wl4[576];
  __shared__ float part[4][4][256];
  int t = threadIdx.x;
  int wv = t >> 6, px = t & 63;
  {
    float* wlf = (float*)wl4;
    for (int idx = t; idx < 2304; idx += 256)
      wlf[idx] = c1w[(size_t)(o0 + (idx & 3)) * 576 + (idx >> 2)];
  }
  float mask[6]; int rcl[6];
#pragma unroll
  for (int k = 0; k < 6; ++k) {
    int ri = row0 - 1 + k;
    mask[k] = (ri >= 0 && ri < 64) ? 1.f : 0.f;
    rcl[k] = ri < 0 ? 0 : (ri > 63 ? 63 : ri);
  }
  int c0 = wv * 16;
  const float* base = ws + OB_OFF + (size_t)b * CN + (size_t)c0 * N_ + px;
  float r[16][6];
#pragma unroll
  for (int i = 0; i < 16; ++i)
#pragma unroll
    for (int k = 0; k < 6; ++k)
      r[i][k] = leaky(base[(size_t)i * N_ + (size_t)rcl[k] * 64]) * mask[k];
  float acc[4][4] = {};
  auto tap = [&](int ch, const float* v) {
    float lf[6], rg[6];
#pragma unroll
    for (int k = 0; k < 6; ++k) {
      lf[k] = __shfl_up(v[k], 1, 64);   if (px == 0)  lf[k] = 0.f;
      rg[k] = __shfl_down(v[k], 1, 64); if (px == 63) rg[k] = 0.f;
    }
#pragma unroll
    for (int ky = 0; ky < 3; ++ky) {
      float4 w0 = wl4[ch * 9 + ky * 3 + 0];
      float4 w1 = wl4[ch * 9 + ky * 3 + 1];
      float4 w2 = wl4[ch * 9 + ky * 3 + 2];
#pragma unroll
      for (int j = 0; j < 4; ++j) {
        int k = j + ky;
        acc[j][0] = fmaf(w0.x, lf[k], fmaf(w1.x, v[k], fmaf(w2.x, rg[k], acc[j][0])));
        acc[j][1] = fmaf(w0.y, lf[k], fmaf(w1.y, v[k], fmaf(w2.y, rg[k], acc[j][1])));
        acc[j][2] = fmaf(w0.z, lf[k], fmaf(w1.z, v[k], fmaf(w2.z, rg[k], acc[j][2])));
        acc[j][3] = fmaf(w0.w, lf[k], fmaf(w1.w, v[k], fmaf(w2.w, rg[k], acc[j][3])));
      }
    }
  };
  __syncthreads();
#pragma unroll
  for (int i = 0; i < 16; ++i) tap(c0 + i, r[i]);
#pragma unroll
  for (int j = 0; j < 4; ++j)
#pragma unroll
    for (int oo = 0; oo < 4; ++oo) part[wv][oo][j * 64 + px] = acc[j][oo];
  __syncthreads();
  int oc = t >> 6;
  float bb = c1b[o0 + oc];
  float* ub = ws + UB_OFF + (size_t)b * CN;
#pragma unroll
  for (int j = 0; j < 4; ++j) {
    int jp = j * 64 + px;
    float s = (part[0][oc][jp] + part[1][oc][jp]) + (part[2][oc][jp] + part[3][oc][jp]);
    ub[(size_t)(o0 + oc) * N_ + (size_t)(row0 + j) * 64 + px] = leaky(s + bb);
  }
}

// ---------------- K6: final, channel-split + fused sc dot, 2 rows/wave (R9 proven) ----------------
__global__ __launch_bounds__(256) void k_final(const float* __restrict__ ws,
                                               const float* __restrict__ c2w,
                                               const float* __restrict__ c2b,
                                               const float* __restrict__ scw,
                                               const float* __restrict__ scb,
                                               float* __restrict__ out) {
  int blk = blockIdx.x;  // 1024 = b*512 + og*32 + rt
  int rt = blk & 31; blk >>= 5;
  int og  = blk & 15; blk >>= 4;
  int b   = blk;
  int o0 = og * 4;
  int row0 = rt * 2;
  __shared__ __align__(16) float4 wl4[576];
  __shared__ __align__(16) float4 scl4[64];
  __shared__ float part[4][4][128];
  __shared__ float part2[4][4][128];
  int t = threadIdx.x;
  int wv = t >> 6, px = t & 63;
  {
    float* wlf = (float*)wl4;
    for (int idx = t; idx < 2304; idx += 256)
      wlf[idx] = c2w[(size_t)(o0 + (idx & 3)) * 576 + (idx >> 2)];
    float* sclf = (float*)scl4;
    if (t < 256) {
      int idx = t;
      sclf[idx] = scw[(size_t)(o0 + (idx & 3)) * 64 + (idx >> 2)];
    }
  }
  float mask[4]; int rcl[4];
#pragma unroll
  for (int k = 0; k < 4; ++k) {
    int ri = row0 - 1 + k;
    mask[k] = (ri >= 0 && ri < 64) ? 1.f : 0.f;
    rcl[k] = ri < 0 ? 0 : (ri > 63 ? 63 : ri);
  }
  int c0 = wv * 16;
  const float* base = ws + UB_OFF + (size_t)b * CN + (size_t)c0 * N_ + px;
  const float* obb  = ws + OB_OFF + (size_t)b * CN + (size_t)c0 * N_ + px;
  float r[4][16], ob[2][16];
#pragma unroll
  for (int i = 0; i < 16; ++i) {
#pragma unroll
    for (int k = 0; k < 4; ++k)
      r[k][i] = base[(size_t)i * N_ + (size_t)rcl[k] * 64] * mask[k];
#pragma unroll
    for (int j = 0; j < 2; ++j)
      ob[j][i] = obb[(size_t)i * N_ + (size_t)(row0 + j) * 64];
  }
  float acc[2][4] = {};
  float scp[2][4] = {};
  auto tap = [&](int ch, float v0, float v1, float v2, float v3) {
    float v[4] = {v0, v1, v2, v3};
    float lf[4], rg[4];
#pragma unroll
    for (int k = 0; k < 4; ++k) {
      lf[k] = __shfl_up(v[k], 1, 64);   if (px == 0)  lf[k] = 0.f;
      rg[k] = __shfl_down(v[k], 1, 64); if (px == 63) rg[k] = 0.f;
    }
#pragma unroll
    for (int ky = 0; ky < 3; ++ky) {
      float4 w0 = wl4[ch * 9 + ky * 3 + 0];
      float4 w1 = wl4[ch * 9 + ky * 3 + 1];
      float4 w2 = wl4[ch * 9 + ky * 3 + 2];
#pragma unroll
      for (int j = 0; j < 2; ++j) {
        int k = j + ky;
        acc[j][0] = fmaf(w0.x, lf[k], fmaf(w1.x, v[k], fmaf(w2.x, rg[k], acc[j][0])));
        acc[j][1] = fmaf(w0.y, lf[k], fmaf(w1.y, v[k], fmaf(w2.y, rg[k], acc[j][1])));
        acc[j][2] = fmaf(w0.z, lf[k], fmaf(w1.z, v[k], fmaf(w2.z, rg[k], acc[j][2])));
        acc[j][3] = fmaf(w0.w, lf[k], fmaf(w1.w, v[k], fmaf(w2.w, rg[k], acc[j][3])));
      }
    }
  };
  __syncthreads();
#pragma unroll
  for (int i = 0; i < 16; ++i) {
    tap(c0 + i, r[0][i], r[1][i], r[2][i], r[3][i]);
    float4 s4 = scl4[c0 + i];
#pragma unroll
    for (int j = 0; j < 2; ++j) {
      scp[j][0] = fmaf(s4.x, ob[j][i], scp[j][0]);
      scp[j][1] = fmaf(s4.y, ob[j][i], scp[j][1]);
      scp[j][2] = fmaf(s4.z, ob[j][i], scp[j][2]);
      scp[j][3] = fmaf(s4.w, ob[j][i], scp[j][3]);
    }
  }
#pragma unroll
  for (int j = 0; j < 2; ++j)
#pragma unroll
    for (int oo = 0; oo < 4; ++oo) {
      part[wv][oo][j * 64 + px] = acc[j][oo];
      part2[wv][oo][j * 64 + px] = scp[j][oo];
    }
  __syncthreads();
  int oc = t >> 6;
  float c2bv = c2b[o0 + oc];
  float scbv = scb[o0 + oc];
  const float* go = ws + GO_OFF + (size_t)b * CN;
  float* ob_out = out + (size_t)b * CN;
#pragma unroll
  for (int j = 0; j < 2; ++j) {
    int jp = j * 64 + px;
    float s  = (part[0][oc][jp] + part[1][oc][jp]) + (part[2][oc][jp] + part[3][oc][jp]);
    float sc = (part2[0][oc][jp] + part2[1][oc][jp]) + (part2[2][oc][jp] + part2[3][oc][jp]);
    size_t pix = (size_t)(row0 + j) * 64 + px;
    float gvv = go[(size_t)(o0 + oc) * N_ + pix];
    ob_out[(size_t)(o0 + oc) * N_ + pix] = (s + c2bv) + (sc + scbv) * gvv;
  }
}

extern "C" void kernel_launch(void* const* d_in, const int* in_sizes, int n_in,
                              void* d_out, int out_size, void* d_ws, size_t ws_size,
                              hipStream_t stream) {
  const float* x     = (const float*)d_in[0];
  const float* guide = (const float*)d_in[1];
  const float* lin_w = (const float*)d_in[2];
  const float* lin_b = (const float*)d_in[3];
  const float* cw    = (const float*)d_in[4];
  const float* xq_w  = (const float*)d_in[5];
  const float* xq_b  = (const float*)d_in[6];
  const float* xk_w  = (const float*)d_in[7];
  const float* xk_b  = (const float*)d_in[8];
  const float* xv_w  = (const float*)d_in[9];
  const float* xv_b  = (const float*)d_in[10];
  const float* gq_w  = (const float*)d_in[11];
  const float* gq_b  = (const float*)d_in[12];
  const float* gk_w  = (const float*)d_in[13];
  const float* gk_b  = (const float*)d_in[14];
  const float* gamma = (const float*)d_in[15];
  const float* alpha = (const float*)d_in[16];
  const float* c1_w  = (const float*)d_in[17];
  const float* c1_b  = (const float*)d_in[18];
  const float* c2_w  = (const float*)d_in[19];
  const float* c2_b  = (const float*)d_in[20];
  const float* sc_w  = (const float*)d_in[21];
  const float* sc_b  = (const float*)d_in[22];
  float* out = (float*)d_out;
  float* ws = (float*)d_ws;

  k_ca<<<256, 64, 0, stream>>>(x, guide, lin_w, lin_b,
                               xq_w, xk_w, xv_w, gq_w, gk_w, ws);
  k_coordconv<<<1024, 256, 0, stream>>>(x, guide, cw, ws);
  k_proj<<<640, 256, 0, stream>>>(ws, xq_b, xk_b, xv_b, gq_b, gk_b);
  k_attn<<<512, 256, 0, stream>>>(ws);
  k_merge<<<512, 256, 0, stream>>>(ws, gamma, alpha);
  k_conv1<<<512, 256, 0, stream>>>(ws, c1_w, c1_b);
  k_final<<<1024, 256, 0, stream>>>(ws, c2_w, c2_b, sc_w, sc_b, out);
}